// Round 11
// baseline (754.700 us; speedup 1.0000x reference)
//
#include <hip/hip_runtime.h>
#include <hip/hip_bf16.h>

#define NN 20000
#define NE 320000
#define TOUT 12
#define DEGMAX 96
#define MR 80       // rows per LSTM block (5 row-tiles of 16)
#define NBLK 250    // 20000/80 exactly -> ONE block per CU, single round
#define NCPL 13     // GX chunks in LDS (of 20); 7 in named regs

typedef __bf16 bf16x8 __attribute__((ext_vector_type(8)));
typedef float float4v __attribute__((ext_vector_type(4)));

#define LD8(p) (*(const bf16x8*)(p))
#define MFMA16(a,b,c) __builtin_amdgcn_mfma_f32_16x16x32_bf16((a),(b),(c),0,0,0)

__device__ __forceinline__ float bf2f(const __hip_bfloat16 v){ return __bfloat162float(v); }
__device__ __forceinline__ __hip_bfloat16 f2bf(float v){ return __float2bfloat16(v); }
__device__ __forceinline__ float sigmoidr_(float x){ return __builtin_amdgcn_rcpf(1.f + __expf(-x)); }
__device__ __forceinline__ float tanhr_(float x){ return 1.f - 2.f*__builtin_amdgcn_rcpf(__expf(2.f*x) + 1.f); }
__device__ __forceinline__ float rdf(const void* p, int i, int f32){
  return f32 ? ((const float*)p)[i] : __bfloat162float(((const __hip_bfloat16*)p)[i]);
}

// ---------------- input dtype detector ----------------
__global__ void k_detect(const void* xraw, int* flag){
  __shared__ int cnt;
  if(threadIdx.x == 0) cnt = 0;
  __syncthreads();
  const unsigned* w = (const unsigned*)xraw;
  int local = 0;
  for(int i = threadIdx.x; i < 4096; i += 256){
    unsigned b = (w[i] >> 8) & 0x7F;
    if(b >= 0x33 && b <= 0x3F) local++;
  }
  atomicAdd(&cnt, local);
  __syncthreads();
  if(threadIdx.x == 0) *flag = (cnt > 2048) ? 0 : 1;   // 1 => fp32 inputs
}

// guard signature: constant 256.0 everywhere (fp32 out)
__global__ void k_fail(float* out, int n){
  int i = blockIdx.x*256 + threadIdx.x;
  if(i < n) out[i] = 256.0f;
}

// ---------------- CSR build ----------------
__global__ void k_count(const int* __restrict__ dst, int* __restrict__ deg){
  int e = blockIdx.x*256 + threadIdx.x;
  if(e < NE){
    unsigned d = (unsigned)dst[e];
    if(d < NN) atomicAdd(&deg[d], 1);
  }
}

__global__ void k_scan(const int* __restrict__ deg, int* __restrict__ offp, int* __restrict__ cursor){
  __shared__ int part[256];
  __shared__ int excl[257];
  const int CH = (NN + 255)/256;
  int tid = threadIdx.x;
  int lo = tid*CH;
  int hi = lo + CH; if(hi > NN) hi = NN;
  int s = 0;
  for(int i=lo;i<hi;i++) s += deg[i];
  part[tid] = s;
  __syncthreads();
  if(tid == 0){
    int run = 0;
    for(int i=0;i<256;i++){ excl[i] = run; run += part[i]; }
    excl[256] = run;
  }
  __syncthreads();
  int run = excl[tid];
  for(int i=lo;i<hi;i++){ offp[i] = run; cursor[i] = run; run += deg[i]; }
  if(tid == 0) offp[NN] = excl[256];
}

__global__ void k_fill(const int* __restrict__ src, const int* __restrict__ dst,
                       int* __restrict__ cursor, int* __restrict__ csr_src){
  int e = blockIdx.x*256 + threadIdx.x;
  if(e >= NE) return;
  unsigned d = (unsigned)dst[e];
  if(d >= NN) return;
  unsigned p = (unsigned)atomicAdd(&cursor[d], 1);
  if(p < NE){
    unsigned sv = (unsigned)src[e];
    csr_src[p] = (sv < NN) ? (int)sv : 0;
  }
}

// ---------------- weight prep (fused) ----------------
__global__ void k_prep(const void* __restrict__ w_src, const void* __restrict__ w_dst,
                       const void* __restrict__ w_hh, const void* __restrict__ wih,
                       const void* __restrict__ mlp_w, const int* __restrict__ flag,
                       __hip_bfloat16* __restrict__ wsrcT, __hip_bfloat16* __restrict__ wdstT,
                       __hip_bfloat16* __restrict__ whhp, __hip_bfloat16* __restrict__ wihb,
                       __hip_bfloat16* __restrict__ mlpT){
  int tid = blockIdx.x*256 + threadIdx.x;
  int f = *flag;
  if(tid < 131072){
    int l = tid >> 16, r = tid & 65535, o = r >> 8, i = r & 255;
    wsrcT[tid] = f2bf(rdf(w_src, l*65536 + i*256 + o, f));
    wdstT[tid] = f2bf(rdf(w_dst, l*65536 + i*256 + o, f));
  }
  if(tid < 262144){
    whhp[tid] = f2bf(rdf(w_hh, tid, f));
    wihb[tid] = f2bf(rdf(wih, tid, f));
  }
  if(tid < 65536){
    int k = tid >> 8, j = tid & 255;
    mlpT[tid] = f2bf(rdf(mlp_w, j*257 + 1 + k, f));
  }
}

// u[g], bc[g] via parallel block reduction; small vectors folded into blocks 0/1
__global__ void k_prep_ub(const void* __restrict__ wih, const void* __restrict__ mlp_w,
                          const void* __restrict__ mlp_b,
                          const void* __restrict__ b_ih, const void* __restrict__ b_hh,
                          const void* __restrict__ att, const void* __restrict__ gbias,
                          const void* __restrict__ init_w, const void* __restrict__ init_b,
                          const void* __restrict__ out_w, const void* __restrict__ out_b,
                          const int* __restrict__ flag,
                          float* __restrict__ u, float* __restrict__ bc,
                          float* __restrict__ attf, float* __restrict__ gbiasf,
                          float* __restrict__ initwf, float* __restrict__ outwf,
                          float* __restrict__ sc){
  __shared__ float su[256], sb[256];
  int g = blockIdx.x, j = threadIdx.x, f = *flag;
  float w = rdf(wih, g*256 + j, f);
  su[j] = w * rdf(mlp_w, j*257, f);
  sb[j] = w * rdf(mlp_b, j, f);
  if(g < 2){
    int i = g*256 + j;
    attf[i] = rdf(att, i, f);
    gbiasf[i] = rdf(gbias, i, f);
  }
  if(g == 0){
    initwf[j] = rdf(init_w, j, f);
    outwf[j]  = rdf(out_w, j, f);
    if(j == 0){ sc[0] = rdf(init_b, 0, f); sc[1] = rdf(out_b, 0, f); }
  }
  __syncthreads();
  for(int s=128; s>0; s>>=1){
    if(j < s){ su[j] += su[j+s]; sb[j] += sb[j+s]; }
    __syncthreads();
  }
  if(j == 0){ u[g] = su[0]; bc[g] = sb[0] + rdf(b_ih, g, f) + rdf(b_hh, g, f); }
}

// rank-1 fold: Whh2 = Whh + u (x) out_w   (decoder prev-feedback folded into Whh)
__global__ void k_fold(const __hip_bfloat16* __restrict__ whh_pl,
                       const float* __restrict__ u_vec, const float* __restrict__ outwf,
                       __hip_bfloat16* __restrict__ whh2_pl){
  int i = blockIdx.x*256 + threadIdx.x;   // 0..262143
  whh2_pl[i] = f2bf(bf2f(whh_pl[i]) + u_vec[i >> 8]*outwf[i & 255]);
}

// ---------------- LSTM weight pack v3: gate-interleaved column halves ----------------
// Phase P covers hidden dims [P*128, P*128+128). Fragment ntl = gate g.
// brow (original W row) = g*256 + P*128 + cs*16 + l16, so each thread's 4 fragments
// (ntl 0..3) are the 4 gates of the SAME 16 hidden dims -> a column-half phase
// finishes its c/h elements completely (no crossing gate state) AND the two phases
// stream DISJOINT weight halves (512KB/step total).
__global__ void k_pack3(const __hip_bfloat16* __restrict__ Wpl, const __hip_bfloat16* __restrict__ W2pl,
                        const __hip_bfloat16* __restrict__ Wcpl,
                        __hip_bfloat16* __restrict__ WhhP, __hip_bfloat16* __restrict__ Whh2P,
                        __hip_bfloat16* __restrict__ WcP){
  int idx = blockIdx.x*256 + threadIdx.x;   // 0..32767
  if(idx >= 32768) return;
  int P    = idx >> 14;
  int cs   = (idx >> 11) & 7;
  int kidx = (idx >> 8) & 7;
  int ntl  = (idx >> 6) & 3;
  int lane = idx & 63;
  int l16 = lane & 15, quad = lane >> 4;
  int brow = ntl*256 + P*128 + cs*16 + l16;
  int srcofs = brow*256 + kidx*32 + quad*8;
  int dst = idx*8;
  *(bf16x8*)(WhhP + dst)  = LD8(Wpl + srcofs);
  *(bf16x8*)(Whh2P + dst) = LD8(W2pl + srcofs);
  *(bf16x8*)(WcP + dst)   = LD8(Wcpl + srcofs);
}

// pack the 4 projection matrices [256x256] into dual-gemm fragment order
__global__ void k_pack2(const __hip_bfloat16* __restrict__ wsrcT,
                        const __hip_bfloat16* __restrict__ wdstT,
                        __hip_bfloat16* __restrict__ wprojP){
  int idx = blockIdx.x*256 + threadIdx.x;   // 0..32767
  if(idx >= 32768) return;
  int m = idx >> 13;
  int fi = idx & 8191;
  int l = m >> 1, role = m & 1;
  int kidx = fi >> 10;
  int nt = (fi >> 6) & 15;
  int lane = fi & 63;
  int l16 = lane & 15, quad = lane >> 4;
  const __hip_bfloat16* src = (role ? wdstT : wsrcT) + l*65536;
  int srcofs = (nt*16 + l16)*256 + kidx*32 + quad*8;
  *(bf16x8*)(wprojP + (size_t)m*65536 + fi*8) = LD8(src + srcofs);
}

// ---------------- NT GEMM: Cb[m,n] = sum_k A[m,k]*B[n,k], M parametrized --------------
__global__ __launch_bounds__(256) void k_gemm_nt_bf(const __hip_bfloat16* __restrict__ A,
                                                    const __hip_bfloat16* __restrict__ B,
                                                    __hip_bfloat16* __restrict__ Cb, int M){
  int wave = threadIdx.x >> 6;
  int lane = threadIdx.x & 63;
  int l16 = lane & 15, quad = lane >> 4, quad8 = quad*8;
  int mBase = blockIdx.x*64 + wave*16;
  int nBase = blockIdx.y*64;
  int arow = mBase + l16; if(arow >= M) arow = M-1;
  const __hip_bfloat16* aptr = A + (size_t)arow*256 + quad8;
  float4v acc[4];
  #pragma unroll
  for(int nt=0;nt<4;nt++){ acc[nt][0]=0.f; acc[nt][1]=0.f; acc[nt][2]=0.f; acc[nt][3]=0.f; }
  for(int k0=0;k0<256;k0+=32){
    bf16x8 a = LD8(aptr + k0);
    #pragma unroll
    for(int nt=0;nt<4;nt++){
      const __hip_bfloat16* bptr = B + (size_t)(nBase + nt*16 + l16)*256 + k0 + quad8;
      acc[nt] = MFMA16(a, LD8(bptr), acc[nt]);
    }
  }
  #pragma unroll
  for(int nt=0;nt<4;nt++){
    int col = nBase + nt*16 + l16;
    #pragma unroll
    for(int r=0;r<4;r++){
      int row = mBase + quad*4 + r;
      if(row < M) Cb[(size_t)row*256 + col] = f2bf(acc[nt][r]);
    }
  }
}

// ---------------- dual projection GEMM: Q = A@Bsrc^T, P = A@Bdst^T (in-place) --------
__global__ __launch_bounds__(512, 2) void k_gemm_dual(__hip_bfloat16* __restrict__ P,
                                                      const void* __restrict__ xraw,
                                                      const int* __restrict__ flag,
                                                      int layer0,
                                                      const __hip_bfloat16* __restrict__ BsrcP,
                                                      const __hip_bfloat16* __restrict__ BdstP,
                                                      __hip_bfloat16* __restrict__ Q){
  __shared__ __hip_bfloat16 sA[64*264];
  int tid = threadIdx.x;
  int mBase = blockIdx.x*64;
  {
    int r = tid >> 3;
    int c0 = (tid & 7)*32;
    int grow = mBase + r; if(grow >= NN) grow = NN-1;
    if(layer0){
      int f = *flag;
      #pragma unroll
      for(int j=0;j<32;j++) sA[r*264 + c0 + j] = f2bf(rdf(xraw, grow*256 + c0 + j, f));
    }else{
      const __hip_bfloat16* srcp = P + (size_t)grow*256 + c0;
      #pragma unroll
      for(int j=0;j<4;j++) *(bf16x8*)(&sA[r*264 + c0 + j*8]) = LD8(srcp + j*8);
    }
  }
  __syncthreads();
  int w8 = tid >> 6;
  int w = w8 & 3;
  int role = w8 >> 2;
  int lane = tid&63, l16 = lane&15, quad = lane>>4, quad8 = quad*8;
  const __hip_bfloat16* B = role ? BdstP : BsrcP;
  __hip_bfloat16* C = role ? P : Q;
  const __hip_bfloat16* arow = &sA[(w*16 + l16)*264 + quad8];
  float4v acc[16];
  #pragma unroll
  for(int nt=0;nt<16;nt++){ acc[nt][0]=0.f; acc[nt][1]=0.f; acc[nt][2]=0.f; acc[nt][3]=0.f; }
  for(int kidx=0;kidx<8;kidx++){
    bf16x8 a = *(const bf16x8*)(arow + kidx*32);
    const __hip_bfloat16* bbase = B + (kidx<<13) + (lane<<3);
    #pragma unroll
    for(int nt=0;nt<16;nt++)
      acc[nt] = MFMA16(a, LD8(bbase + (nt<<9)), acc[nt]);
  }
  #pragma unroll
  for(int nt=0;nt<16;nt++){
    int col = nt*16 + l16;
    #pragma unroll
    for(int r=0;r<4;r++){
      int row = mBase + w*16 + quad*4 + r;
      if(row < NN) C[(size_t)row*256 + col] = f2bf(acc[nt][r]);
    }
  }
}

// ---------------- GAT edge phase v3: ONLINE softmax, single gather pass --------------
// r11: the old structure gathered every Q row TWICE (logits pass with 16-lane groups,
// then aggregation pass) = 2 x 20000 x deg x 512B = ~320MB random reads per layer;
// r10 showed instruction-count fixes don't move it -> it's gather-bound. Online
// softmax fuses the passes: per edge, ALL 256 threads read the row once (coalesced
// 512B), logit_h = wave-reduce (wave w IS head w: dims w*64..+63), then running-max
// rescale of per-thread {acc,den}. Halves gather traffic, drops slog + 2 barriers,
// LDS -> 384B (occupancy cap 8 blocks/CU). Next row explicitly prefetched.
__global__ __launch_bounds__(256) void k_node_fused(const __hip_bfloat16* __restrict__ Q,
                                                    __hip_bfloat16* __restrict__ P,
                                                    const int* __restrict__ offp,
                                                    const int* __restrict__ csr_src,
                                                    const float* __restrict__ attf,
                                                    const float* __restrict__ gbiasf){
  __shared__ int ssrc[DEGMAX];
  int node = blockIdx.x;
  int tid = threadIdx.x;            // tid == hidden dim d; wave (tid>>6) == head
  int s0 = offp[node], s1 = offp[node+1];
  if(s0 < 0) s0 = 0; if(s0 > NE) s0 = NE;
  if(s1 < s0) s1 = s0; if(s1 > NE) s1 = NE;
  int deg = s1 - s0; if(deg > DEGMAX) deg = DEGMAX;
  if(tid < deg){
    unsigned sv = (unsigned)csr_src[s0 + tid];
    ssrc[tid] = (sv < NN) ? (int)sv : 0;
  }
  __syncthreads();
  float pr = bf2f(P[(size_t)node*256 + tid]);   // xr[dst][d]
  float at = attf[tid];
  float m = -1e30f, den = 0.f, acc = 0.f;
  float qv = (deg > 0) ? bf2f(Q[(size_t)ssrc[0]*256 + tid]) : 0.f;
  for(int i=0;i<deg;i++){
    float qn = (i+1 < deg) ? bf2f(Q[(size_t)ssrc[i+1]*256 + tid]) : 0.f;  // prefetch
    float v = qv + pr;
    v = (v > 0.f) ? v : 0.2f*v;                 // LeakyReLU
    float part = v * at;
    part += __shfl_xor(part, 1, 64);            // reduce over this head's 64 dims
    part += __shfl_xor(part, 2, 64);
    part += __shfl_xor(part, 4, 64);
    part += __shfl_xor(part, 8, 64);
    part += __shfl_xor(part, 16, 64);
    part += __shfl_xor(part, 32, 64);
    if(part > m){                               // wave-uniform branch
      float sc = __expf(m - part);
      acc *= sc; den *= sc; m = part;
    }
    float wgt = __expf(part - m);
    den += wgt;
    acc += wgt * qv;
    qv = qn;
  }
  float o = (den > 0.f) ? acc * (1.f/den) : 0.f;
  o += gbiasf[tid];
  o = (o > 0.f) ? o : (__expf(o) - 1.f);        // ELU
  P[(size_t)node*256 + tid] = f2bf(o);
}

// ---------------- persistent LSTM v6b (r8, PROVEN 271us): hidden-half split ----------
// Reverted exactly to r8: 2 waves/SIMD 256-reg regime is the only spill-clean one
// (r9 MR32 + r10 16-wave both spilled at the 128-reg cap). gateB chunk map: cpa EVEN
// {10,12,14,16,18} -> sgx/gg1/gg3/gg5; cpb_ ODD {11,13,15,17,19} -> sgx/gg0/gg2/gg4/gg6.
__global__ __launch_bounds__(512, 1) void k_lstm80(const __hip_bfloat16* __restrict__ ctx,
                                                   const __hip_bfloat16* __restrict__ WcP,
                                                   const __hip_bfloat16* __restrict__ WhhP,
                                                   const __hip_bfloat16* __restrict__ Whh2P,
                                                   const float* __restrict__ u_vec,
                                                   const float* __restrict__ bc_vec,
                                                   const float* __restrict__ initwf,
                                                   const float* __restrict__ outwf,
                                                   const float* __restrict__ sc,
                                                   float* __restrict__ out){
  __shared__ __hip_bfloat16 sgx[NCPL*4096]; // 106,496B GX chunks [cp][thread][8]
  __shared__ __hip_bfloat16 sh[MR*264];     // 42,240B h tile (bank-padded)
  __shared__ float spartw[2][MR*16];        // 10,240B out-proj partials (step-parity dbuf)
  __shared__ float sprev0[MR];              // 320B step-0 prev
  float* spart = (float*)sgx;               // prologue-only overlay (2KB of sgx)
  int tid = threadIdx.x;
  int mBase = blockIdx.x*MR;
  int cs = tid>>6, lane = tid&63, l16 = lane&15, quad = lane>>4, quad8 = quad*8;
  int phase = (blockIdx.x >> 3) & 7;
  int j0 = cs*16 + l16;          // phase-A hidden dim
  int j1 = 128 + j0;             // phase-B hidden dim
  // load h0 = ctx tile
  #pragma unroll
  for(int p=0;p<3;p++){
    int r = p*32 + (tid >> 4);
    if(r < MR){
      int c0 = (tid & 15)*16;
      const __hip_bfloat16* srcp = ctx + (size_t)(mBase + r)*256 + c0;
      *(bf16x8*)(&sh[r*264 + c0])     = LD8(srcp);
      *(bf16x8*)(&sh[r*264 + c0 + 8]) = LD8(srcp + 8);
    }
  }
  __syncthreads();
  // prev0 = ctx @ init_w + init_b   (spart overlays sgx; reads done before GX writes)
  #pragma unroll
  for(int p=0;p<3;p++){
    int r = p*32 + (tid >> 4);
    int c0 = (tid & 15)*16;
    float part = 0.f;
    if(r < MR){
      #pragma unroll
      for(int j=0;j<16;j++) part += bf2f(sh[r*264 + c0 + j]) * initwf[c0 + j];
    }
    spart[tid] = part;
    __syncthreads();
    if(tid < 32 && p*32 + tid < MR){
      float s = 0.f;
      #pragma unroll
      for(int j=0;j<16;j++) s += spart[tid*16 + j];
      sprev0[p*32 + tid] = s + sc[0];
    }
    __syncthreads();
  }
  float ow0 = outwf[j0], ow1 = outwf[j1];
  float outb = sc[1];
  // GX phase: GX' = ctx@Wc^T + bc + u*out_b, fragment layout = step layout.
  // cp = P*10 + rt*2 + half; cp 0..12 -> LDS, 13..19 -> gg0..gg6
  bf16x8 gg0, gg1, gg2, gg3, gg4, gg5, gg6;
  {
    float bcl[8];   // [P*4+g]
    #pragma unroll
    for(int g=0;g<4;g++){
      bcl[g]   = bc_vec[g*256 + j0] + u_vec[g*256 + j0]*outb;
      bcl[4+g] = bc_vec[g*256 + j1] + u_vec[g*256 + j1]*outb;
    }
    #pragma unroll
    for(int P2=0;P2<2;P2++){
      float4v acc[20];
      #pragma unroll
      for(int nt=0;nt<20;nt++){ acc[nt][0]=0.f; acc[nt][1]=0.f; acc[nt][2]=0.f; acc[nt][3]=0.f; }
      #pragma unroll 2
      for(int ki=0;ki<8;ki++){
        int kidx = (ki + phase) & 7;
        int k0 = kidx*32;
        bf16x8 a0 = *(const bf16x8*)(&sh[l16*264 + k0 + quad8]);
        bf16x8 a1 = *(const bf16x8*)(&sh[(16 + l16)*264 + k0 + quad8]);
        bf16x8 a2 = *(const bf16x8*)(&sh[(32 + l16)*264 + k0 + quad8]);
        bf16x8 a3 = *(const bf16x8*)(&sh[(48 + l16)*264 + k0 + quad8]);
        bf16x8 a4 = *(const bf16x8*)(&sh[(64 + l16)*264 + k0 + quad8]);
        const __hip_bfloat16* bbase = WcP + P2*131072 + (((cs<<3) + kidx)<<11) + (lane<<3);
        #pragma unroll
        for(int ntl=0;ntl<4;ntl++){
          bf16x8 b = LD8(bbase + (ntl<<9));
          acc[ntl]     = MFMA16(a0, b, acc[ntl]);
          acc[4+ntl]   = MFMA16(a1, b, acc[4+ntl]);
          acc[8+ntl]   = MFMA16(a2, b, acc[8+ntl]);
          acc[12+ntl]  = MFMA16(a3, b, acc[12+ntl]);
          acc[16+ntl]  = MFMA16(a4, b, acc[16+ntl]);
        }
      }
      #pragma unroll
      for(int rt=0;rt<5;rt++)
        #pragma unroll
        for(int half=0;half<2;half++){
          bf16x8 v;
          #pragma unroll
          for(int rr=0;rr<2;rr++)
            #pragma unroll
            for(int g=0;g<4;g++){
              int r = half*2 + rr;
              v[rr*4+g] = (__bf16)f2bf(acc[rt*4 + g][r] + bcl[P2*4+g]);
            }
          const int cp = P2*10 + rt*2 + half;   // compile-time
          if(cp < NCPL) *(bf16x8*)(&sgx[cp*4096 + tid*8]) = v;
          else if(cp == 13) gg0 = v;
          else if(cp == 14) gg1 = v;
          else if(cp == 15) gg2 = v;
          else if(cp == 16) gg3 = v;
          else if(cp == 17) gg4 = v;
          else if(cp == 18) gg5 = v;
          else              gg6 = v;
        }
    }
  }
  // no barrier: sgx slots are own-thread; sh unmodified until step-0 gateB (after S1)
  float creg[40];   // [P*20 + rt*4 + r]
  #pragma unroll
  for(int i=0;i<40;i++) creg[i] = 0.f;
  #pragma unroll 1
  for(int step=0; step<TOUT; step++){
    const __hip_bfloat16* W = (step == 0) ? WhhP : Whh2P;
    int sb = step & 1;
    float4v acc[20];
    // ---- MFMA-A: hidden half 0 (W cols 0..511 repacked) ----
    #pragma unroll
    for(int nt=0;nt<20;nt++){ acc[nt][0]=0.f; acc[nt][1]=0.f; acc[nt][2]=0.f; acc[nt][3]=0.f; }
    #pragma unroll 2
    for(int ki=0;ki<8;ki++){
      int kidx = (ki + phase) & 7;
      int k0 = kidx*32;
      bf16x8 a0 = *(const bf16x8*)(&sh[l16*264 + k0 + quad8]);
      bf16x8 a1 = *(const bf16x8*)(&sh[(16 + l16)*264 + k0 + quad8]);
      bf16x8 a2 = *(const bf16x8*)(&sh[(32 + l16)*264 + k0 + quad8]);
      bf16x8 a3 = *(const bf16x8*)(&sh[(48 + l16)*264 + k0 + quad8]);
      bf16x8 a4 = *(const bf16x8*)(&sh[(64 + l16)*264 + k0 + quad8]);
      const __hip_bfloat16* bbase = W + (((cs<<3) + kidx)<<11) + (lane<<3);
      #pragma unroll
      for(int ntl=0;ntl<4;ntl++){
        bf16x8 b = LD8(bbase + (ntl<<9));
        acc[ntl]     = MFMA16(a0, b, acc[ntl]);
        acc[4+ntl]   = MFMA16(a1, b, acc[4+ntl]);
        acc[8+ntl]   = MFMA16(a2, b, acc[8+ntl]);
        acc[12+ntl]  = MFMA16(a3, b, acc[12+ntl]);
        acc[16+ntl]  = MFMA16(a4, b, acc[16+ntl]);
      }
    }
    // ---- gateA: finish hidden half 0; h held in regs (sh still readable by B) ----
    float hA[20];
    #pragma unroll
    for(int rt=0; rt<5; rt++){
      bf16x8 ga = *(const bf16x8*)(&sgx[(rt*2)*4096 + tid*8]);
      bf16x8 gb = *(const bf16x8*)(&sgx[(rt*2+1)*4096 + tid*8]);
      float hsum[4];
      #pragma unroll
      for(int r=0;r<4;r++){
        int row = rt*16 + quad*4 + r;
        int jb = (r&1)*4;
        float gx0, gx1, gx2, gx3;
        if(r < 2){
          gx0 = bf2f((__hip_bfloat16)ga[jb]);   gx1 = bf2f((__hip_bfloat16)ga[jb+1]);
          gx2 = bf2f((__hip_bfloat16)ga[jb+2]); gx3 = bf2f((__hip_bfloat16)ga[jb+3]);
        }else{
          gx0 = bf2f((__hip_bfloat16)gb[jb]);   gx1 = bf2f((__hip_bfloat16)gb[jb+1]);
          gx2 = bf2f((__hip_bfloat16)gb[jb+2]); gx3 = bf2f((__hip_bfloat16)gb[jb+3]);
        }
        float g0 = acc[rt*4 + 0][r] + gx0;
        float g1 = acc[rt*4 + 1][r] + gx1;
        float g2 = acc[rt*4 + 2][r] + gx2;
        float g3 = acc[rt*4 + 3][r] + gx3;
        if(step == 0){
          float pd = sprev0[row] - outb;   // stored GX includes +u*out_b
          g0 += pd*u_vec[j0];
          g1 += pd*u_vec[256 + j0];
          g2 += pd*u_vec[512 + j0];
          g3 += pd*u_vec[768 + j0];
        }
        float iv = sigmoidr_(g0), fv = sigmoidr_(g1);
        float gv = tanhr_(g2),    ov = sigmoidr_(g3);
        float cn = fv*creg[rt*4 + r] + iv*gv;
        creg[rt*4 + r] = cn;
        float hn = ov * tanhr_(cn);
        hA[rt*4 + r] = hn;
        hsum[r] = hn * ow0;
      }
      #pragma unroll
      for(int r=0;r<4;r++){
        hsum[r] += __shfl_xor(hsum[r], 1, 64);
        hsum[r] += __shfl_xor(hsum[r], 2, 64);
        hsum[r] += __shfl_xor(hsum[r], 4, 64);
        hsum[r] += __shfl_xor(hsum[r], 8, 64);
      }
      if(l16 == 0){
        #pragma unroll
        for(int r=0;r<4;r++)
          spartw[sb][(rt*16 + quad*4 + r)*16 + cs*2] = hsum[r];
      }
    }
    // ---- MFMA-B: hidden half 1 (W cols 512..1023 repacked), acc regs reused ----
    #pragma unroll
    for(int nt=0;nt<20;nt++){ acc[nt][0]=0.f; acc[nt][1]=0.f; acc[nt][2]=0.f; acc[nt][3]=0.f; }
    #pragma unroll 2
    for(int ki=0;ki<8;ki++){
      int kidx = (ki + phase) & 7;
      int k0 = kidx*32;
      bf16x8 a0 = *(const bf16x8*)(&sh[l16*264 + k0 + quad8]);
      bf16x8 a1 = *(const bf16x8*)(&sh[(16 + l16)*264 + k0 + quad8]);
      bf16x8 a2 = *(const bf16x8*)(&sh[(32 + l16)*264 + k0 + quad8]);
      bf16x8 a3 = *(const bf16x8*)(&sh[(48 + l16)*264 + k0 + quad8]);
      bf16x8 a4 = *(const bf16x8*)(&sh[(64 + l16)*264 + k0 + quad8]);
      const __hip_bfloat16* bbase = W + 131072 + (((cs<<3) + kidx)<<11) + (lane<<3);
      #pragma unroll
      for(int ntl=0;ntl<4;ntl++){
        bf16x8 b = LD8(bbase + (ntl<<9));
        acc[ntl]     = MFMA16(a0, b, acc[ntl]);
        acc[4+ntl]   = MFMA16(a1, b, acc[4+ntl]);
        acc[8+ntl]   = MFMA16(a2, b, acc[8+ntl]);
        acc[12+ntl]  = MFMA16(a3, b, acc[12+ntl]);
        acc[16+ntl]  = MFMA16(a4, b, acc[16+ntl]);
      }
    }
    __syncthreads();   // S1: all sh reads of this step done (A and B phases)
    // ---- gateB: finish hidden half 1; write BOTH h halves into sh ----
    #pragma unroll
    for(int rt=0; rt<5; rt++){
      const int cpa = 10 + rt*2, cpb_ = 11 + rt*2;
      // cpa is EVEN: {10,12,14,16,18}; cpb_ is ODD: {11,13,15,17,19}
      bf16x8 ga, gb;
      if(cpa < NCPL)      ga = *(const bf16x8*)(&sgx[cpa*4096 + tid*8]);   // 10,12
      else if(cpa == 14)  ga = gg1;
      else if(cpa == 16)  ga = gg3;
      else                ga = gg5;    // cpa == 18
      if(cpb_ < NCPL)     gb = *(const bf16x8*)(&sgx[cpb_*4096 + tid*8]);  // 11
      else if(cpb_ == 13) gb = gg0;
      else if(cpb_ == 15) gb = gg2;
      else if(cpb_ == 17) gb = gg4;
      else                gb = gg6;    // cpb_ == 19
      float hsum[4];
      #pragma unroll
      for(int r=0;r<4;r++){
        int row = rt*16 + quad*4 + r;
        int jb = (r&1)*4;
        float gx0, gx1, gx2, gx3;
        if(r < 2){
          gx0 = bf2f((__hip_bfloat16)ga[jb]);   gx1 = bf2f((__hip_bfloat16)ga[jb+1]);
          gx2 = bf2f((__hip_bfloat16)ga[jb+2]); gx3 = bf2f((__hip_bfloat16)ga[jb+3]);
        }else{
          gx0 = bf2f((__hip_bfloat16)gb[jb]);   gx1 = bf2f((__hip_bfloat16)gb[jb+1]);
          gx2 = bf2f((__hip_bfloat16)gb[jb+2]); gx3 = bf2f((__hip_bfloat16)gb[jb+3]);
        }
        float g0 = acc[rt*4 + 0][r] + gx0;
        float g1 = acc[rt*4 + 1][r] + gx1;
        float g2 = acc[rt*4 + 2][r] + gx2;
        float g3 = acc[rt*4 + 3][r] + gx3;
        if(step == 0){
          float pd = sprev0[row] - outb;
          g0 += pd*u_vec[j1];
          g1 += pd*u_vec[256 + j1];
          g2 += pd*u_vec[512 + j1];
          g3 += pd*u_vec[768 + j1];
        }
        float iv = sigmoidr_(g0), fv = sigmoidr_(g1);
        float gv = tanhr_(g2),    ov = sigmoidr_(g3);
        float cn = fv*creg[20 + rt*4 + r] + iv*gv;
        creg[20 + rt*4 + r] = cn;
        float hn = ov * tanhr_(cn);
        sh[row*264 + j0] = f2bf(hA[rt*4 + r]);
        sh[row*264 + j1] = f2bf(hn);
        hsum[r] = hn * ow1;
      }
      #pragma unroll
      for(int r=0;r<4;r++){
        hsum[r] += __shfl_xor(hsum[r], 1, 64);
        hsum[r] += __shfl_xor(hsum[r], 2, 64);
        hsum[r] += __shfl_xor(hsum[r], 4, 64);
        hsum[r] += __shfl_xor(hsum[r], 8, 64);
      }
      if(l16 == 0){
        #pragma unroll
        for(int r=0;r<4;r++)
          spartw[sb][(rt*16 + quad*4 + r)*16 + cs*2 + 1] = hsum[r];
      }
    }
    __syncthreads();   // S2: sh + spartw writes visible
    if(tid < MR){
      float s = outb;
      #pragma unroll
      for(int c=0;c<16;c++) s += spartw[sb][tid*16 + c];
      out[(size_t)(mBase + tid)*TOUT + step] = s;
    }
    // next step's gateA writes spartw[sb^1] -> no hazard with this reduce
  }
}

// ---------------- launch ----------------
extern "C" void kernel_launch(void* const* d_in, const int* in_sizes, int n_in,
                              void* d_out, int out_size, void* d_ws, size_t ws_size,
                              hipStream_t stream){
  const void* x      = d_in[0];
  const int*  ei     = (const int*)d_in[1];
  const void* w_src  = d_in[2];
  const void* w_dst  = d_in[3];
  const void* att    = d_in[4];
  const void* gbias  = d_in[5];
  const void* mlp_w  = d_in[6];
  const void* mlp_b  = d_in[7];
  const void* w_ih   = d_in[8];
  const void* w_hh   = d_in[9];
  const void* b_ih   = d_in[10];
  const void* b_hh   = d_in[11];
  const void* init_w = d_in[12];
  const void* init_b = d_in[13];
  const void* out_w  = d_in[14];
  const void* out_b  = d_in[15];
  float* out = (float*)d_out;
  const int* srcp = ei;
  const int* dstp = ei + NE;
  (void)in_sizes; (void)n_in;

  char* ws = (char*)d_ws;
  size_t off = 0;
  auto alloc = [&](size_t bytes)->void*{
    void* p = ws + off;
    off += (bytes + 255) & ~(size_t)255;
    return p;
  };
  __hip_bfloat16* P = (__hip_bfloat16*)alloc((size_t)NN*256*2);
  __hip_bfloat16* Q = (__hip_bfloat16*)alloc((size_t)NN*256*2);
  int* deg      = (int*)alloc((size_t)NN*4);
  int* offp     = (int*)alloc((size_t)(NN+1)*4);
  int* cursor   = (int*)alloc((size_t)NN*4);
  int* csr_src  = (int*)alloc((size_t)NE*4);
  __hip_bfloat16* wsrcT   = (__hip_bfloat16*)alloc((size_t)131072*2);
  __hip_bfloat16* wdstT   = (__hip_bfloat16*)alloc((size_t)131072*2);
  __hip_bfloat16* wprojP  = (__hip_bfloat16*)alloc((size_t)4*65536*2);
  __hip_bfloat16* whh_pl  = (__hip_bfloat16*)alloc((size_t)262144*2);
  __hip_bfloat16* whh2_pl = (__hip_bfloat16*)alloc((size_t)262144*2);
  __hip_bfloat16* Wc_pl   = (__hip_bfloat16*)alloc((size_t)262144*2);
  __hip_bfloat16* WhhP    = (__hip_bfloat16*)alloc((size_t)262144*2);
  __hip_bfloat16* Whh2P   = (__hip_bfloat16*)alloc((size_t)262144*2);
  __hip_bfloat16* WcP     = (__hip_bfloat16*)alloc((size_t)262144*2);
  __hip_bfloat16* wihb    = (__hip_bfloat16*)alloc((size_t)262144*2);
  __hip_bfloat16* mlpT    = (__hip_bfloat16*)alloc((size_t)65536*2);
  float* u_vec  = (float*)alloc(1024*4);
  float* bc_vec = (float*)alloc(1024*4);
  float* attf   = (float*)alloc(512*4);
  float* gbiasf = (float*)alloc(512*4);
  float* initwf = (float*)alloc(256*4);
  float* outwf  = (float*)alloc(256*4);
  float* sc     = (float*)alloc(2*4);
  int*   flag   = (int*)alloc(4);
  // total ~29 MB

  if(off > ws_size){
    k_fail<<<(out_size + 255)/256, 256, 0, stream>>>(out, out_size);
    return;
  }

  // dtype detect + CSR + prep
  k_detect<<<1, 256, 0, stream>>>(x, flag);
  hipMemsetAsync(deg, 0, (size_t)NN*4, stream);
  hipMemsetAsync(csr_src, 0xFF, (size_t)NE*4, stream);
  k_count<<<NE/256, 256, 0, stream>>>(dstp, deg);
  k_scan<<<1, 256, 0, stream>>>(deg, offp, cursor);
  k_fill<<<NE/256, 256, 0, stream>>>(srcp, dstp, cursor, csr_src);
  k_prep<<<1024, 256, 0, stream>>>(w_src, w_dst, w_hh, w_ih, mlp_w, flag,
                                   wsrcT, wdstT, whh_pl, wihb, mlpT);
  k_prep_ub<<<1024, 256, 0, stream>>>(w_ih, mlp_w, mlp_b, b_ih, b_hh, att, gbias,
                                      init_w, init_b, out_w, out_b, flag,
                                      u_vec, bc_vec, attf, gbiasf, initwf, outwf, sc);
  {
    dim3 gwc(16, 4);
    k_gemm_nt_bf<<<gwc, 256, 0, stream>>>(wihb, mlpT, Wc_pl, 1024);   // Wc = Wih @ mlpT^T
  }
  k_fold<<<1024, 256, 0, stream>>>(whh_pl, u_vec, outwf, whh2_pl);
  k_pack3<<<128, 256, 0, stream>>>(whh_pl, whh2_pl, Wc_pl, WhhP, Whh2P, WcP);
  k_pack2<<<128, 256, 0, stream>>>(wsrcT, wdstT, wprojP);

  // GAT layers: dual projection (layer0 reads raw x), then online-softmax edge phase
  for(int l=0;l<2;l++){
    k_gemm_dual<<<313, 512, 0, stream>>>(P, x, flag, (l == 0) ? 1 : 0,
                                         wprojP + (size_t)(l*2)*65536,
                                         wprojP + (size_t)(l*2+1)*65536, Q);
    k_node_fused<<<NN, 256, 0, stream>>>(Q, P, offp, csr_src, attf + l*256, gbiasf + l*256);
  }

  // persistent LSTM decoder: hidden-half split, disjoint streams, single round (r8)
  k_lstm80<<<NBLK, 512, 0, stream>>>(P, WcP, WhhP, Whh2P, u_vec, bc_vec,
                                     initwf, outwf, sc, out);
}

// Round 12
// 632.150 us; speedup vs baseline: 1.1939x; 1.1939x over previous
//
#include <hip/hip_runtime.h>
#include <hip/hip_bf16.h>

#define NN 20000
#define NE 320000
#define TOUT 12
#define DEGMAX 96
#define NPB 4       // nodes per GAT edge-phase block
#define MR 80       // rows per LSTM block (5 row-tiles of 16)
#define NBLK 250    // 20000/80 exactly -> ONE block per CU, single round
#define NCPL 13     // GX chunks in LDS (of 20); 7 in named regs

typedef __bf16 bf16x8 __attribute__((ext_vector_type(8)));
typedef float float4v __attribute__((ext_vector_type(4)));

#define LD8(p) (*(const bf16x8*)(p))
#define MFMA16(a,b,c) __builtin_amdgcn_mfma_f32_16x16x32_bf16((a),(b),(c),0,0,0)

__device__ __forceinline__ float bf2f(const __hip_bfloat16 v){ return __bfloat162float(v); }
__device__ __forceinline__ __hip_bfloat16 f2bf(float v){ return __float2bfloat16(v); }
__device__ __forceinline__ float sigmoidr_(float x){ return __builtin_amdgcn_rcpf(1.f + __expf(-x)); }
__device__ __forceinline__ float tanhr_(float x){ return 1.f - 2.f*__builtin_amdgcn_rcpf(__expf(2.f*x) + 1.f); }
__device__ __forceinline__ float rdf(const void* p, int i, int f32){
  return f32 ? ((const float*)p)[i] : __bfloat162float(((const __hip_bfloat16*)p)[i]);
}

// ---------------- input dtype detector ----------------
__global__ void k_detect(const void* xraw, int* flag){
  __shared__ int cnt;
  if(threadIdx.x == 0) cnt = 0;
  __syncthreads();
  const unsigned* w = (const unsigned*)xraw;
  int local = 0;
  for(int i = threadIdx.x; i < 4096; i += 256){
    unsigned b = (w[i] >> 8) & 0x7F;
    if(b >= 0x33 && b <= 0x3F) local++;
  }
  atomicAdd(&cnt, local);
  __syncthreads();
  if(threadIdx.x == 0) *flag = (cnt > 2048) ? 0 : 1;   // 1 => fp32 inputs
}

// guard signature: constant 256.0 everywhere (fp32 out)
__global__ void k_fail(float* out, int n){
  int i = blockIdx.x*256 + threadIdx.x;
  if(i < n) out[i] = 256.0f;
}

// ---------------- CSR build ----------------
__global__ void k_count(const int* __restrict__ dst, int* __restrict__ deg){
  int e = blockIdx.x*256 + threadIdx.x;
  if(e < NE){
    unsigned d = (unsigned)dst[e];
    if(d < NN) atomicAdd(&deg[d], 1);
  }
}

__global__ void k_scan(const int* __restrict__ deg, int* __restrict__ offp, int* __restrict__ cursor){
  __shared__ int part[256];
  __shared__ int excl[257];
  const int CH = (NN + 255)/256;
  int tid = threadIdx.x;
  int lo = tid*CH;
  int hi = lo + CH; if(hi > NN) hi = NN;
  int s = 0;
  for(int i=lo;i<hi;i++) s += deg[i];
  part[tid] = s;
  __syncthreads();
  if(tid == 0){
    int run = 0;
    for(int i=0;i<256;i++){ excl[i] = run; run += part[i]; }
    excl[256] = run;
  }
  __syncthreads();
  int run = excl[tid];
  for(int i=lo;i<hi;i++){ offp[i] = run; cursor[i] = run; run += deg[i]; }
  if(tid == 0) offp[NN] = excl[256];
}

__global__ void k_fill(const int* __restrict__ src, const int* __restrict__ dst,
                       int* __restrict__ cursor, int* __restrict__ csr_src){
  int e = blockIdx.x*256 + threadIdx.x;
  if(e >= NE) return;
  unsigned d = (unsigned)dst[e];
  if(d >= NN) return;
  unsigned p = (unsigned)atomicAdd(&cursor[d], 1);
  if(p < NE){
    unsigned sv = (unsigned)src[e];
    csr_src[p] = (sv < NN) ? (int)sv : 0;
  }
}

// ---------------- weight prep (fused) ----------------
__global__ void k_prep(const void* __restrict__ w_src, const void* __restrict__ w_dst,
                       const void* __restrict__ w_hh, const void* __restrict__ wih,
                       const void* __restrict__ mlp_w, const int* __restrict__ flag,
                       __hip_bfloat16* __restrict__ wsrcT, __hip_bfloat16* __restrict__ wdstT,
                       __hip_bfloat16* __restrict__ whhp, __hip_bfloat16* __restrict__ wihb,
                       __hip_bfloat16* __restrict__ mlpT){
  int tid = blockIdx.x*256 + threadIdx.x;
  int f = *flag;
  if(tid < 131072){
    int l = tid >> 16, r = tid & 65535, o = r >> 8, i = r & 255;
    wsrcT[tid] = f2bf(rdf(w_src, l*65536 + i*256 + o, f));
    wdstT[tid] = f2bf(rdf(w_dst, l*65536 + i*256 + o, f));
  }
  if(tid < 262144){
    whhp[tid] = f2bf(rdf(w_hh, tid, f));
    wihb[tid] = f2bf(rdf(wih, tid, f));
  }
  if(tid < 65536){
    int k = tid >> 8, j = tid & 255;
    mlpT[tid] = f2bf(rdf(mlp_w, j*257 + 1 + k, f));
  }
}

// u[g], bc[g] via parallel block reduction; small vectors folded into blocks 0/1
__global__ void k_prep_ub(const void* __restrict__ wih, const void* __restrict__ mlp_w,
                          const void* __restrict__ mlp_b,
                          const void* __restrict__ b_ih, const void* __restrict__ b_hh,
                          const void* __restrict__ att, const void* __restrict__ gbias,
                          const void* __restrict__ init_w, const void* __restrict__ init_b,
                          const void* __restrict__ out_w, const void* __restrict__ out_b,
                          const int* __restrict__ flag,
                          float* __restrict__ u, float* __restrict__ bc,
                          float* __restrict__ attf, float* __restrict__ gbiasf,
                          float* __restrict__ initwf, float* __restrict__ outwf,
                          float* __restrict__ sc){
  __shared__ float su[256], sb[256];
  int g = blockIdx.x, j = threadIdx.x, f = *flag;
  float w = rdf(wih, g*256 + j, f);
  su[j] = w * rdf(mlp_w, j*257, f);
  sb[j] = w * rdf(mlp_b, j, f);
  if(g < 2){
    int i = g*256 + j;
    attf[i] = rdf(att, i, f);
    gbiasf[i] = rdf(gbias, i, f);
  }
  if(g == 0){
    initwf[j] = rdf(init_w, j, f);
    outwf[j]  = rdf(out_w, j, f);
    if(j == 0){ sc[0] = rdf(init_b, 0, f); sc[1] = rdf(out_b, 0, f); }
  }
  __syncthreads();
  for(int s=128; s>0; s>>=1){
    if(j < s){ su[j] += su[j+s]; sb[j] += sb[j+s]; }
    __syncthreads();
  }
  if(j == 0){ u[g] = su[0]; bc[g] = sb[0] + rdf(b_ih, g, f) + rdf(b_hh, g, f); }
}

// ---------------- LSTM weight pack v4: gate-interleaved halves + INLINE rank-1 fold --
// Phase P covers hidden dims [P*128, P*128+128). Fragment ntl = gate g.
// brow (original W row) = g*256 + P*128 + cs*16 + l16. Whh2 = Whh + u (x) out_w is
// computed INLINE (replaces the separate k_fold kernel + whh2_pl buffer).
__global__ void k_pack3(const __hip_bfloat16* __restrict__ Wpl,
                        const __hip_bfloat16* __restrict__ Wcpl,
                        const float* __restrict__ u_vec, const float* __restrict__ outwf,
                        __hip_bfloat16* __restrict__ WhhP, __hip_bfloat16* __restrict__ Whh2P,
                        __hip_bfloat16* __restrict__ WcP){
  int idx = blockIdx.x*256 + threadIdx.x;   // 0..32767
  if(idx >= 32768) return;
  int P    = idx >> 14;
  int cs   = (idx >> 11) & 7;
  int kidx = (idx >> 8) & 7;
  int ntl  = (idx >> 6) & 3;
  int lane = idx & 63;
  int l16 = lane & 15, quad = lane >> 4;
  int brow = ntl*256 + P*128 + cs*16 + l16;
  int col0 = kidx*32 + quad*8;
  int srcofs = brow*256 + col0;
  int dst = idx*8;
  bf16x8 wv = LD8(Wpl + srcofs);
  *(bf16x8*)(WhhP + dst) = wv;
  float uu = u_vec[brow];
  bf16x8 w2;
  #pragma unroll
  for(int jj=0;jj<8;jj++)
    w2[jj] = (__bf16)f2bf(bf2f((__hip_bfloat16)wv[jj]) + uu*outwf[col0 + jj]);
  *(bf16x8*)(Whh2P + dst) = w2;
  *(bf16x8*)(WcP + dst)   = LD8(Wcpl + srcofs);
}

// pack the 4 projection matrices [256x256] into dual-gemm fragment order
__global__ void k_pack2(const __hip_bfloat16* __restrict__ wsrcT,
                        const __hip_bfloat16* __restrict__ wdstT,
                        __hip_bfloat16* __restrict__ wprojP){
  int idx = blockIdx.x*256 + threadIdx.x;   // 0..32767
  if(idx >= 32768) return;
  int m = idx >> 13;
  int fi = idx & 8191;
  int l = m >> 1, role = m & 1;
  int kidx = fi >> 10;
  int nt = (fi >> 6) & 15;
  int lane = fi & 63;
  int l16 = lane & 15, quad = lane >> 4;
  const __hip_bfloat16* src = (role ? wdstT : wsrcT) + l*65536;
  int srcofs = (nt*16 + l16)*256 + kidx*32 + quad*8;
  *(bf16x8*)(wprojP + (size_t)m*65536 + fi*8) = LD8(src + srcofs);
}

// ---------------- NT GEMM: Cb[m,n] = sum_k A[m,k]*B[n,k], M parametrized --------------
__global__ __launch_bounds__(256) void k_gemm_nt_bf(const __hip_bfloat16* __restrict__ A,
                                                    const __hip_bfloat16* __restrict__ B,
                                                    __hip_bfloat16* __restrict__ Cb, int M){
  int wave = threadIdx.x >> 6;
  int lane = threadIdx.x & 63;
  int l16 = lane & 15, quad = lane >> 4, quad8 = quad*8;
  int mBase = blockIdx.x*64 + wave*16;
  int nBase = blockIdx.y*64;
  int arow = mBase + l16; if(arow >= M) arow = M-1;
  const __hip_bfloat16* aptr = A + (size_t)arow*256 + quad8;
  float4v acc[4];
  #pragma unroll
  for(int nt=0;nt<4;nt++){ acc[nt][0]=0.f; acc[nt][1]=0.f; acc[nt][2]=0.f; acc[nt][3]=0.f; }
  for(int k0=0;k0<256;k0+=32){
    bf16x8 a = LD8(aptr + k0);
    #pragma unroll
    for(int nt=0;nt<4;nt++){
      const __hip_bfloat16* bptr = B + (size_t)(nBase + nt*16 + l16)*256 + k0 + quad8;
      acc[nt] = MFMA16(a, LD8(bptr), acc[nt]);
    }
  }
  #pragma unroll
  for(int nt=0;nt<4;nt++){
    int col = nBase + nt*16 + l16;
    #pragma unroll
    for(int r=0;r<4;r++){
      int row = mBase + quad*4 + r;
      if(row < M) Cb[(size_t)row*256 + col] = f2bf(acc[nt][r]);
    }
  }
}

// ---------------- dual projection GEMM: Q = A@Bsrc^T, P = A@Bdst^T (in-place) --------
__global__ __launch_bounds__(512, 2) void k_gemm_dual(__hip_bfloat16* __restrict__ P,
                                                      const void* __restrict__ xraw,
                                                      const int* __restrict__ flag,
                                                      int layer0,
                                                      const __hip_bfloat16* __restrict__ BsrcP,
                                                      const __hip_bfloat16* __restrict__ BdstP,
                                                      __hip_bfloat16* __restrict__ Q){
  __shared__ __hip_bfloat16 sA[64*264];
  int tid = threadIdx.x;
  int mBase = blockIdx.x*64;
  {
    int r = tid >> 3;
    int c0 = (tid & 7)*32;
    int grow = mBase + r; if(grow >= NN) grow = NN-1;
    if(layer0){
      int f = *flag;
      #pragma unroll
      for(int j=0;j<32;j++) sA[r*264 + c0 + j] = f2bf(rdf(xraw, grow*256 + c0 + j, f));
    }else{
      const __hip_bfloat16* srcp = P + (size_t)grow*256 + c0;
      #pragma unroll
      for(int j=0;j<4;j++) *(bf16x8*)(&sA[r*264 + c0 + j*8]) = LD8(srcp + j*8);
    }
  }
  __syncthreads();
  int w8 = tid >> 6;
  int w = w8 & 3;
  int role = w8 >> 2;
  int lane = tid&63, l16 = lane&15, quad = lane>>4, quad8 = quad*8;
  const __hip_bfloat16* B = role ? BdstP : BsrcP;
  __hip_bfloat16* C = role ? P : Q;
  const __hip_bfloat16* arow = &sA[(w*16 + l16)*264 + quad8];
  float4v acc[16];
  #pragma unroll
  for(int nt=0;nt<16;nt++){ acc[nt][0]=0.f; acc[nt][1]=0.f; acc[nt][2]=0.f; acc[nt][3]=0.f; }
  for(int kidx=0;kidx<8;kidx++){
    bf16x8 a = *(const bf16x8*)(arow + kidx*32);
    const __hip_bfloat16* bbase = B + (kidx<<13) + (lane<<3);
    #pragma unroll
    for(int nt=0;nt<16;nt++)
      acc[nt] = MFMA16(a, LD8(bbase + (nt<<9)), acc[nt]);
  }
  #pragma unroll
  for(int nt=0;nt<16;nt++){
    int col = nt*16 + l16;
    #pragma unroll
    for(int r=0;r<4;r++){
      int row = mBase + w*16 + quad*4 + r;
      if(row < NN) C[(size_t)row*256 + col] = f2bf(acc[nt][r]);
    }
  }
}

// ---------------- GAT edge phase: two-pass (r8-proven), 4 nodes per block ------------
// r12: r11 proved online softmax is WORSE (+106us: serial per-edge shfl chain kills
// ILP); two-pass structure restored. New: NPB=4 nodes per block (grid 5000) amortizes
// per-block fixed costs (dispatch, setup); att loads hoisted (node-invariant). Logits
// use r10's vectorized form (2xLD8/lane, correctness-proven, ~neutral-to-better).
__global__ __launch_bounds__(256) void k_node_fused(const __hip_bfloat16* __restrict__ Q,
                                                    __hip_bfloat16* __restrict__ P,
                                                    const int* __restrict__ offp,
                                                    const int* __restrict__ csr_src,
                                                    const float* __restrict__ attf,
                                                    const float* __restrict__ gbiasf){
  __shared__ float slog[DEGMAX*4];
  __shared__ int ssrc[DEGMAX];
  int tid = threadIdx.x;
  int w = tid>>6, lane = tid&63;
  int eSlot = lane>>4, li = lane&15;   // 16-lane group per edge; lane owns d=li*16..+15
  float attl[16];
  #pragma unroll
  for(int j=0;j<16;j++) attl[j] = attf[li*16 + j];
  float gb = gbiasf[tid];
  int hd = tid>>6;
  #pragma unroll 1
  for(int nn=0; nn<NPB; nn++){
    int node = blockIdx.x*NPB + nn;
    int s0 = offp[node], s1 = offp[node+1];
    if(s0 < 0) s0 = 0; if(s0 > NE) s0 = NE;
    if(s1 < s0) s1 = s0; if(s1 > NE) s1 = NE;
    int deg = s1 - s0; if(deg > DEGMAX) deg = DEGMAX;
    if(tid < deg){
      unsigned sv = (unsigned)csr_src[s0 + tid];
      ssrc[tid] = (sv < NN) ? (int)sv : 0;
    }
    __syncthreads();
    float prl[16];
    {
      const __hip_bfloat16* prow = P + (size_t)node*256 + li*16;
      bf16x8 p0 = LD8(prow), p1 = LD8(prow + 8);
      #pragma unroll
      for(int j=0;j<8;j++){ prl[j] = bf2f((__hip_bfloat16)p0[j]); prl[8+j] = bf2f((__hip_bfloat16)p1[j]); }
    }
    for(int base=0; base<deg; base+=16){
      int e = base + w*4 + eSlot;
      bool valid = (e < deg);
      const __hip_bfloat16* qrow = Q + (size_t)ssrc[valid ? e : 0]*256 + li*16;
      bf16x8 q0 = LD8(qrow), q1 = LD8(qrow + 8);
      float part = 0.f;
      #pragma unroll
      for(int j=0;j<16;j++){
        float v = bf2f((__hip_bfloat16)(j<8 ? q0[j] : q1[j-8])) + prl[j];
        v = (v > 0.f) ? v : 0.2f*v;
        part += v * attl[j];
      }
      part += __shfl_xor(part, 1, 64);
      part += __shfl_xor(part, 2, 64);
      if((li & 3) == 0 && valid) slog[e*4 + (li>>2)] = part;
    }
    __syncthreads();
    {
      int hh = tid >> 6;          // one wave per head
      int li64 = tid & 63;
      float m = -1e30f;
      for(int i=li64; i<deg; i+=64) m = fmaxf(m, slog[i*4+hh]);
      #pragma unroll
      for(int s=1; s<64; s<<=1) m = fmaxf(m, __shfl_xor(m, s, 64));
      float den = 0.f;
      for(int i=li64; i<deg; i+=64) den += __expf(slog[i*4+hh] - m);
      #pragma unroll
      for(int s=1; s<64; s<<=1) den += __shfl_xor(den, s, 64);
      float inv = (den > 0.f) ? 1.f/den : 0.f;
      for(int i=li64; i<deg; i+=64) slog[i*4+hh] = __expf(slog[i*4+hh] - m)*inv;
    }
    __syncthreads();
    float acc = 0.f;
    for(int i=0;i<deg;i++) acc += slog[i*4+hd] * bf2f(Q[(size_t)ssrc[i]*256 + tid]);
    acc += gb;
    acc = (acc > 0.f) ? acc : (__expf(acc) - 1.f);   // ELU
    P[(size_t)node*256 + tid] = f2bf(acc);
    __syncthreads();   // protect ssrc/slog reuse by next node
  }
}

// ---------------- persistent LSTM v6b (r8, PROVEN 272us): hidden-half split ----------
// 2 waves/SIMD 256-reg regime is the only spill-clean one (r9 MR32 + r10 16-wave both
// spilled at the 128-reg cap). gateB chunk map: cpa EVEN {10,12,14,16,18} ->
// sgx/gg1/gg3/gg5; cpb_ ODD {11,13,15,17,19} -> sgx/gg0/gg2/gg4/gg6.
__global__ __launch_bounds__(512, 1) void k_lstm80(const __hip_bfloat16* __restrict__ ctx,
                                                   const __hip_bfloat16* __restrict__ WcP,
                                                   const __hip_bfloat16* __restrict__ WhhP,
                                                   const __hip_bfloat16* __restrict__ Whh2P,
                                                   const float* __restrict__ u_vec,
                                                   const float* __restrict__ bc_vec,
                                                   const float* __restrict__ initwf,
                                                   const float* __restrict__ outwf,
                                                   const float* __restrict__ sc,
                                                   float* __restrict__ out){
  __shared__ __hip_bfloat16 sgx[NCPL*4096]; // 106,496B GX chunks [cp][thread][8]
  __shared__ __hip_bfloat16 sh[MR*264];     // 42,240B h tile (bank-padded)
  __shared__ float spartw[2][MR*16];        // 10,240B out-proj partials (step-parity dbuf)
  __shared__ float sprev0[MR];              // 320B step-0 prev
  float* spart = (float*)sgx;               // prologue-only overlay (2KB of sgx)
  int tid = threadIdx.x;
  int mBase = blockIdx.x*MR;
  int cs = tid>>6, lane = tid&63, l16 = lane&15, quad = lane>>4, quad8 = quad*8;
  int phase = (blockIdx.x >> 3) & 7;
  int j0 = cs*16 + l16;          // phase-A hidden dim
  int j1 = 128 + j0;             // phase-B hidden dim
  // load h0 = ctx tile
  #pragma unroll
  for(int p=0;p<3;p++){
    int r = p*32 + (tid >> 4);
    if(r < MR){
      int c0 = (tid & 15)*16;
      const __hip_bfloat16* srcp = ctx + (size_t)(mBase + r)*256 + c0;
      *(bf16x8*)(&sh[r*264 + c0])     = LD8(srcp);
      *(bf16x8*)(&sh[r*264 + c0 + 8]) = LD8(srcp + 8);
    }
  }
  __syncthreads();
  // prev0 = ctx @ init_w + init_b   (spart overlays sgx; reads done before GX writes)
  #pragma unroll
  for(int p=0;p<3;p++){
    int r = p*32 + (tid >> 4);
    int c0 = (tid & 15)*16;
    float part = 0.f;
    if(r < MR){
      #pragma unroll
      for(int j=0;j<16;j++) part += bf2f(sh[r*264 + c0 + j]) * initwf[c0 + j];
    }
    spart[tid] = part;
    __syncthreads();
    if(tid < 32 && p*32 + tid < MR){
      float s = 0.f;
      #pragma unroll
      for(int j=0;j<16;j++) s += spart[tid*16 + j];
      sprev0[p*32 + tid] = s + sc[0];
    }
    __syncthreads();
  }
  float ow0 = outwf[j0], ow1 = outwf[j1];
  float outb = sc[1];
  // GX phase: GX' = ctx@Wc^T + bc + u*out_b, fragment layout = step layout.
  // cp = P*10 + rt*2 + half; cp 0..12 -> LDS, 13..19 -> gg0..gg6
  bf16x8 gg0, gg1, gg2, gg3, gg4, gg5, gg6;
  {
    float bcl[8];   // [P*4+g]
    #pragma unroll
    for(int g=0;g<4;g++){
      bcl[g]   = bc_vec[g*256 + j0] + u_vec[g*256 + j0]*outb;
      bcl[4+g] = bc_vec[g*256 + j1] + u_vec[g*256 + j1]*outb;
    }
    #pragma unroll
    for(int P2=0;P2<2;P2++){
      float4v acc[20];
      #pragma unroll
      for(int nt=0;nt<20;nt++){ acc[nt][0]=0.f; acc[nt][1]=0.f; acc[nt][2]=0.f; acc[nt][3]=0.f; }
      #pragma unroll 2
      for(int ki=0;ki<8;ki++){
        int kidx = (ki + phase) & 7;
        int k0 = kidx*32;
        bf16x8 a0 = *(const bf16x8*)(&sh[l16*264 + k0 + quad8]);
        bf16x8 a1 = *(const bf16x8*)(&sh[(16 + l16)*264 + k0 + quad8]);
        bf16x8 a2 = *(const bf16x8*)(&sh[(32 + l16)*264 + k0 + quad8]);
        bf16x8 a3 = *(const bf16x8*)(&sh[(48 + l16)*264 + k0 + quad8]);
        bf16x8 a4 = *(const bf16x8*)(&sh[(64 + l16)*264 + k0 + quad8]);
        const __hip_bfloat16* bbase = WcP + P2*131072 + (((cs<<3) + kidx)<<11) + (lane<<3);
        #pragma unroll
        for(int ntl=0;ntl<4;ntl++){
          bf16x8 b = LD8(bbase + (ntl<<9));
          acc[ntl]     = MFMA16(a0, b, acc[ntl]);
          acc[4+ntl]   = MFMA16(a1, b, acc[4+ntl]);
          acc[8+ntl]   = MFMA16(a2, b, acc[8+ntl]);
          acc[12+ntl]  = MFMA16(a3, b, acc[12+ntl]);
          acc[16+ntl]  = MFMA16(a4, b, acc[16+ntl]);
        }
      }
      #pragma unroll
      for(int rt=0;rt<5;rt++)
        #pragma unroll
        for(int half=0;half<2;half++){
          bf16x8 v;
          #pragma unroll
          for(int rr=0;rr<2;rr++)
            #pragma unroll
            for(int g=0;g<4;g++){
              int r = half*2 + rr;
              v[rr*4+g] = (__bf16)f2bf(acc[rt*4 + g][r] + bcl[P2*4+g]);
            }
          const int cp = P2*10 + rt*2 + half;   // compile-time
          if(cp < NCPL) *(bf16x8*)(&sgx[cp*4096 + tid*8]) = v;
          else if(cp == 13) gg0 = v;
          else if(cp == 14) gg1 = v;
          else if(cp == 15) gg2 = v;
          else if(cp == 16) gg3 = v;
          else if(cp == 17) gg4 = v;
          else if(cp == 18) gg5 = v;
          else              gg6 = v;
        }
    }
  }
  // no barrier: sgx slots are own-thread; sh unmodified until step-0 gateB (after S1)
  float creg[40];   // [P*20 + rt*4 + r]
  #pragma unroll
  for(int i=0;i<40;i++) creg[i] = 0.f;
  #pragma unroll 1
  for(int step=0; step<TOUT; step++){
    const __hip_bfloat16* W = (step == 0) ? WhhP : Whh2P;
    int sb = step & 1;
    float4v acc[20];
    // ---- MFMA-A: hidden half 0 (W cols 0..511 repacked) ----
    #pragma unroll
    for(int nt=0;nt<20;nt++){ acc[nt][0]=0.f; acc[nt][1]=0.f; acc[nt][2]=0.f; acc[nt][3]=0.f; }
    #pragma unroll 2
    for(int ki=0;ki<8;ki++){
      int kidx = (ki + phase) & 7;
      int k0 = kidx*32;
      bf16x8 a0 = *(const bf16x8*)(&sh[l16*264 + k0 + quad8]);
      bf16x8 a1 = *(const bf16x8*)(&sh[(16 + l16)*264 + k0 + quad8]);
      bf16x8 a2 = *(const bf16x8*)(&sh[(32 + l16)*264 + k0 + quad8]);
      bf16x8 a3 = *(const bf16x8*)(&sh[(48 + l16)*264 + k0 + quad8]);
      bf16x8 a4 = *(const bf16x8*)(&sh[(64 + l16)*264 + k0 + quad8]);
      const __hip_bfloat16* bbase = W + (((cs<<3) + kidx)<<11) + (lane<<3);
      #pragma unroll
      for(int ntl=0;ntl<4;ntl++){
        bf16x8 b = LD8(bbase + (ntl<<9));
        acc[ntl]     = MFMA16(a0, b, acc[ntl]);
        acc[4+ntl]   = MFMA16(a1, b, acc[4+ntl]);
        acc[8+ntl]   = MFMA16(a2, b, acc[8+ntl]);
        acc[12+ntl]  = MFMA16(a3, b, acc[12+ntl]);
        acc[16+ntl]  = MFMA16(a4, b, acc[16+ntl]);
      }
    }
    // ---- gateA: finish hidden half 0; h held in regs (sh still readable by B) ----
    float hA[20];
    #pragma unroll
    for(int rt=0; rt<5; rt++){
      bf16x8 ga = *(const bf16x8*)(&sgx[(rt*2)*4096 + tid*8]);
      bf16x8 gb = *(const bf16x8*)(&sgx[(rt*2+1)*4096 + tid*8]);
      float hsum[4];
      #pragma unroll
      for(int r=0;r<4;r++){
        int row = rt*16 + quad*4 + r;
        int jb = (r&1)*4;
        float gx0, gx1, gx2, gx3;
        if(r < 2){
          gx0 = bf2f((__hip_bfloat16)ga[jb]);   gx1 = bf2f((__hip_bfloat16)ga[jb+1]);
          gx2 = bf2f((__hip_bfloat16)ga[jb+2]); gx3 = bf2f((__hip_bfloat16)ga[jb+3]);
        }else{
          gx0 = bf2f((__hip_bfloat16)gb[jb]);   gx1 = bf2f((__hip_bfloat16)gb[jb+1]);
          gx2 = bf2f((__hip_bfloat16)gb[jb+2]); gx3 = bf2f((__hip_bfloat16)gb[jb+3]);
        }
        float g0 = acc[rt*4 + 0][r] + gx0;
        float g1 = acc[rt*4 + 1][r] + gx1;
        float g2 = acc[rt*4 + 2][r] + gx2;
        float g3 = acc[rt*4 + 3][r] + gx3;
        if(step == 0){
          float pd = sprev0[row] - outb;   // stored GX includes +u*out_b
          g0 += pd*u_vec[j0];
          g1 += pd*u_vec[256 + j0];
          g2 += pd*u_vec[512 + j0];
          g3 += pd*u_vec[768 + j0];
        }
        float iv = sigmoidr_(g0), fv = sigmoidr_(g1);
        float gv = tanhr_(g2),    ov = sigmoidr_(g3);
        float cn = fv*creg[rt*4 + r] + iv*gv;
        creg[rt*4 + r] = cn;
        float hn = ov * tanhr_(cn);
        hA[rt*4 + r] = hn;
        hsum[r] = hn * ow0;
      }
      #pragma unroll
      for(int r=0;r<4;r++){
        hsum[r] += __shfl_xor(hsum[r], 1, 64);
        hsum[r] += __shfl_xor(hsum[r], 2, 64);
        hsum[r] += __shfl_xor(hsum[r], 4, 64);
        hsum[r] += __shfl_xor(hsum[r], 8, 64);
      }
      if(l16 == 0){
        #pragma unroll
        for(int r=0;r<4;r++)
          spartw[sb][(rt*16 + quad*4 + r)*16 + cs*2] = hsum[r];
      }
    }
    // ---- MFMA-B: hidden half 1 (W cols 512..1023 repacked), acc regs reused ----
    #pragma unroll
    for(int nt=0;nt<20;nt++){ acc[nt][0]=0.f; acc[nt][1]=0.f; acc[nt][2]=0.f; acc[nt][3]=0.f; }
    #pragma unroll 2
    for(int ki=0;ki<8;ki++){
      int kidx = (ki + phase) & 7;
      int k0 = kidx*32;
      bf16x8 a0 = *(const bf16x8*)(&sh[l16*264 + k0 + quad8]);
      bf16x8 a1 = *(const bf16x8*)(&sh[(16 + l16)*264 + k0 + quad8]);
      bf16x8 a2 = *(const bf16x8*)(&sh[(32 + l16)*264 + k0 + quad8]);
      bf16x8 a3 = *(const bf16x8*)(&sh[(48 + l16)*264 + k0 + quad8]);
      bf16x8 a4 = *(const bf16x8*)(&sh[(64 + l16)*264 + k0 + quad8]);
      const __hip_bfloat16* bbase = W + 131072 + (((cs<<3) + kidx)<<11) + (lane<<3);
      #pragma unroll
      for(int ntl=0;ntl<4;ntl++){
        bf16x8 b = LD8(bbase + (ntl<<9));
        acc[ntl]     = MFMA16(a0, b, acc[ntl]);
        acc[4+ntl]   = MFMA16(a1, b, acc[4+ntl]);
        acc[8+ntl]   = MFMA16(a2, b, acc[8+ntl]);
        acc[12+ntl]  = MFMA16(a3, b, acc[12+ntl]);
        acc[16+ntl]  = MFMA16(a4, b, acc[16+ntl]);
      }
    }
    __syncthreads();   // S1: all sh reads of this step done (A and B phases)
    // ---- gateB: finish hidden half 1; write BOTH h halves into sh ----
    #pragma unroll
    for(int rt=0; rt<5; rt++){
      const int cpa = 10 + rt*2, cpb_ = 11 + rt*2;
      // cpa is EVEN: {10,12,14,16,18}; cpb_ is ODD: {11,13,15,17,19}
      bf16x8 ga, gb;
      if(cpa < NCPL)      ga = *(const bf16x8*)(&sgx[cpa*4096 + tid*8]);   // 10,12
      else if(cpa == 14)  ga = gg1;
      else if(cpa == 16)  ga = gg3;
      else                ga = gg5;    // cpa == 18
      if(cpb_ < NCPL)     gb = *(const bf16x8*)(&sgx[cpb_*4096 + tid*8]);  // 11
      else if(cpb_ == 13) gb = gg0;
      else if(cpb_ == 15) gb = gg2;
      else if(cpb_ == 17) gb = gg4;
      else                gb = gg6;    // cpb_ == 19
      float hsum[4];
      #pragma unroll
      for(int r=0;r<4;r++){
        int row = rt*16 + quad*4 + r;
        int jb = (r&1)*4;
        float gx0, gx1, gx2, gx3;
        if(r < 2){
          gx0 = bf2f((__hip_bfloat16)ga[jb]);   gx1 = bf2f((__hip_bfloat16)ga[jb+1]);
          gx2 = bf2f((__hip_bfloat16)ga[jb+2]); gx3 = bf2f((__hip_bfloat16)ga[jb+3]);
        }else{
          gx0 = bf2f((__hip_bfloat16)gb[jb]);   gx1 = bf2f((__hip_bfloat16)gb[jb+1]);
          gx2 = bf2f((__hip_bfloat16)gb[jb+2]); gx3 = bf2f((__hip_bfloat16)gb[jb+3]);
        }
        float g0 = acc[rt*4 + 0][r] + gx0;
        float g1 = acc[rt*4 + 1][r] + gx1;
        float g2 = acc[rt*4 + 2][r] + gx2;
        float g3 = acc[rt*4 + 3][r] + gx3;
        if(step == 0){
          float pd = sprev0[row] - outb;
          g0 += pd*u_vec[j1];
          g1 += pd*u_vec[256 + j1];
          g2 += pd*u_vec[512 + j1];
          g3 += pd*u_vec[768 + j1];
        }
        float iv = sigmoidr_(g0), fv = sigmoidr_(g1);
        float gv = tanhr_(g2),    ov = sigmoidr_(g3);
        float cn = fv*creg[20 + rt*4 + r] + iv*gv;
        creg[20 + rt*4 + r] = cn;
        float hn = ov * tanhr_(cn);
        sh[row*264 + j0] = f2bf(hA[rt*4 + r]);
        sh[row*264 + j1] = f2bf(hn);
        hsum[r] = hn * ow1;
      }
      #pragma unroll
      for(int r=0;r<4;r++){
        hsum[r] += __shfl_xor(hsum[r], 1, 64);
        hsum[r] += __shfl_xor(hsum[r], 2, 64);
        hsum[r] += __shfl_xor(hsum[r], 4, 64);
        hsum[r] += __shfl_xor(hsum[r], 8, 64);
      }
      if(l16 == 0){
        #pragma unroll
        for(int r=0;r<4;r++)
          spartw[sb][(rt*16 + quad*4 + r)*16 + cs*2 + 1] = hsum[r];
      }
    }
    __syncthreads();   // S2: sh + spartw writes visible
    if(tid < MR){
      float s = outb;
      #pragma unroll
      for(int c=0;c<16;c++) s += spartw[sb][tid*16 + c];
      out[(size_t)(mBase + tid)*TOUT + step] = s;
    }
    // next step's gateA writes spartw[sb^1] -> no hazard with this reduce
  }
}

// ---------------- launch ----------------
extern "C" void kernel_launch(void* const* d_in, const int* in_sizes, int n_in,
                              void* d_out, int out_size, void* d_ws, size_t ws_size,
                              hipStream_t stream){
  const void* x      = d_in[0];
  const int*  ei     = (const int*)d_in[1];
  const void* w_src  = d_in[2];
  const void* w_dst  = d_in[3];
  const void* att    = d_in[4];
  const void* gbias  = d_in[5];
  const void* mlp_w  = d_in[6];
  const void* mlp_b  = d_in[7];
  const void* w_ih   = d_in[8];
  const void* w_hh   = d_in[9];
  const void* b_ih   = d_in[10];
  const void* b_hh   = d_in[11];
  const void* init_w = d_in[12];
  const void* init_b = d_in[13];
  const void* out_w  = d_in[14];
  const void* out_b  = d_in[15];
  float* out = (float*)d_out;
  const int* srcp = ei;
  const int* dstp = ei + NE;
  (void)in_sizes; (void)n_in;

  char* ws = (char*)d_ws;
  size_t off = 0;
  auto alloc = [&](size_t bytes)->void*{
    void* p = ws + off;
    off += (bytes + 255) & ~(size_t)255;
    return p;
  };
  __hip_bfloat16* P = (__hip_bfloat16*)alloc((size_t)NN*256*2);
  __hip_bfloat16* Q = (__hip_bfloat16*)alloc((size_t)NN*256*2);
  int* deg      = (int*)alloc((size_t)NN*4);
  int* offp     = (int*)alloc((size_t)(NN+1)*4);
  int* cursor   = (int*)alloc((size_t)NN*4);
  int* csr_src  = (int*)alloc((size_t)NE*4);
  __hip_bfloat16* wsrcT   = (__hip_bfloat16*)alloc((size_t)131072*2);
  __hip_bfloat16* wdstT   = (__hip_bfloat16*)alloc((size_t)131072*2);
  __hip_bfloat16* wprojP  = (__hip_bfloat16*)alloc((size_t)4*65536*2);
  __hip_bfloat16* whh_pl  = (__hip_bfloat16*)alloc((size_t)262144*2);
  __hip_bfloat16* Wc_pl   = (__hip_bfloat16*)alloc((size_t)262144*2);
  __hip_bfloat16* WhhP    = (__hip_bfloat16*)alloc((size_t)262144*2);
  __hip_bfloat16* Whh2P   = (__hip_bfloat16*)alloc((size_t)262144*2);
  __hip_bfloat16* WcP     = (__hip_bfloat16*)alloc((size_t)262144*2);
  __hip_bfloat16* wihb    = (__hip_bfloat16*)alloc((size_t)262144*2);
  __hip_bfloat16* mlpT    = (__hip_bfloat16*)alloc((size_t)65536*2);
  float* u_vec  = (float*)alloc(1024*4);
  float* bc_vec = (float*)alloc(1024*4);
  float* attf   = (float*)alloc(512*4);
  float* gbiasf = (float*)alloc(512*4);
  float* initwf = (float*)alloc(256*4);
  float* outwf  = (float*)alloc(256*4);
  float* sc     = (float*)alloc(2*4);
  int*   flag   = (int*)alloc(4);
  // total ~28 MB

  if(off > ws_size){
    k_fail<<<(out_size + 255)/256, 256, 0, stream>>>(out, out_size);
    return;
  }

  // dtype detect + CSR + prep
  k_detect<<<1, 256, 0, stream>>>(x, flag);
  hipMemsetAsync(deg, 0, (size_t)NN*4, stream);
  hipMemsetAsync(csr_src, 0xFF, (size_t)NE*4, stream);
  k_count<<<NE/256, 256, 0, stream>>>(dstp, deg);
  k_scan<<<1, 256, 0, stream>>>(deg, offp, cursor);
  k_fill<<<NE/256, 256, 0, stream>>>(srcp, dstp, cursor, csr_src);
  k_prep<<<1024, 256, 0, stream>>>(w_src, w_dst, w_hh, w_ih, mlp_w, flag,
                                   wsrcT, wdstT, whh_pl, wihb, mlpT);
  k_prep_ub<<<1024, 256, 0, stream>>>(w_ih, mlp_w, mlp_b, b_ih, b_hh, att, gbias,
                                      init_w, init_b, out_w, out_b, flag,
                                      u_vec, bc_vec, attf, gbiasf, initwf, outwf, sc);
  {
    dim3 gwc(16, 4);
    k_gemm_nt_bf<<<gwc, 256, 0, stream>>>(wihb, mlpT, Wc_pl, 1024);   // Wc = Wih @ mlpT^T
  }
  k_pack3<<<128, 256, 0, stream>>>(whh_pl, Wc_pl, u_vec, outwf, WhhP, Whh2P, WcP);
  k_pack2<<<128, 256, 0, stream>>>(wsrcT, wdstT, wprojP);

  // GAT layers: dual projection (layer0 reads raw x), then two-pass edge phase
  for(int l=0;l<2;l++){
    k_gemm_dual<<<313, 512, 0, stream>>>(P, x, flag, (l == 0) ? 1 : 0,
                                         wprojP + (size_t)(l*2)*65536,
                                         wprojP + (size_t)(l*2+1)*65536, Q);
    k_node_fused<<<NN/NPB, 256, 0, stream>>>(Q, P, offp, csr_src, attf + l*256, gbiasf + l*256);
  }

  // persistent LSTM decoder: hidden-half split, disjoint streams, single round (r8)
  k_lstm80<<<NBLK, 512, 0, stream>>>(P, WcP, WhhP, Whh2P, u_vec, bc_vec,
                                     initwf, outwf, sc, out);
}

// Round 13
// 626.320 us; speedup vs baseline: 1.2050x; 1.0093x over previous
//
#include <hip/hip_runtime.h>
#include <hip/hip_bf16.h>

#define NN 20000
#define NE 320000
#define TOUT 12
#define DEGMAX 96
#define NPB 10      // nodes per GAT edge-phase block (grid 2000)
#define MR 80       // rows per LSTM block (5 row-tiles of 16)
#define NBLK 250    // 20000/80 exactly -> ONE block per CU, single round
#define NCPL 13     // GX chunks in LDS (of 20); 7 in named regs

typedef __bf16 bf16x8 __attribute__((ext_vector_type(8)));
typedef float float4v __attribute__((ext_vector_type(4)));

#define LD8(p) (*(const bf16x8*)(p))
#define MFMA16(a,b,c) __builtin_amdgcn_mfma_f32_16x16x32_bf16((a),(b),(c),0,0,0)

__device__ __forceinline__ float bf2f(const __hip_bfloat16 v){ return __bfloat162float(v); }
__device__ __forceinline__ __hip_bfloat16 f2bf(float v){ return __float2bfloat16(v); }
__device__ __forceinline__ float sigmoidr_(float x){ return __builtin_amdgcn_rcpf(1.f + __expf(-x)); }
__device__ __forceinline__ float tanhr_(float x){ return 1.f - 2.f*__builtin_amdgcn_rcpf(__expf(2.f*x) + 1.f); }
__device__ __forceinline__ float rdf(const void* p, int i, int f32){
  return f32 ? ((const float*)p)[i] : __bfloat162float(((const __hip_bfloat16*)p)[i]);
}

// ---------------- input dtype detector ----------------
__global__ void k_detect(const void* xraw, int* flag){
  __shared__ int cnt;
  if(threadIdx.x == 0) cnt = 0;
  __syncthreads();
  const unsigned* w = (const unsigned*)xraw;
  int local = 0;
  for(int i = threadIdx.x; i < 4096; i += 256){
    unsigned b = (w[i] >> 8) & 0x7F;
    if(b >= 0x33 && b <= 0x3F) local++;
  }
  atomicAdd(&cnt, local);
  __syncthreads();
  if(threadIdx.x == 0) *flag = (cnt > 2048) ? 0 : 1;   // 1 => fp32 inputs
}

// guard signature: constant 256.0 everywhere (fp32 out)
__global__ void k_fail(float* out, int n){
  int i = blockIdx.x*256 + threadIdx.x;
  if(i < n) out[i] = 256.0f;
}

// ---------------- CSR build ----------------
__global__ void k_count(const int* __restrict__ dst, int* __restrict__ deg){
  int e = blockIdx.x*256 + threadIdx.x;
  if(e < NE){
    unsigned d = (unsigned)dst[e];
    if(d < NN) atomicAdd(&deg[d], 1);
  }
}

__global__ void k_scan(const int* __restrict__ deg, int* __restrict__ offp, int* __restrict__ cursor){
  __shared__ int part[256];
  __shared__ int excl[257];
  const int CH = (NN + 255)/256;
  int tid = threadIdx.x;
  int lo = tid*CH;
  int hi = lo + CH; if(hi > NN) hi = NN;
  int s = 0;
  for(int i=lo;i<hi;i++) s += deg[i];
  part[tid] = s;
  __syncthreads();
  if(tid == 0){
    int run = 0;
    for(int i=0;i<256;i++){ excl[i] = run; run += part[i]; }
    excl[256] = run;
  }
  __syncthreads();
  int run = excl[tid];
  for(int i=lo;i<hi;i++){ offp[i] = run; cursor[i] = run; run += deg[i]; }
  if(tid == 0) offp[NN] = excl[256];
}

__global__ void k_fill(const int* __restrict__ src, const int* __restrict__ dst,
                       int* __restrict__ cursor, int* __restrict__ csr_src){
  int e = blockIdx.x*256 + threadIdx.x;
  if(e >= NE) return;
  unsigned d = (unsigned)dst[e];
  if(d >= NN) return;
  unsigned p = (unsigned)atomicAdd(&cursor[d], 1);
  if(p < NE){
    unsigned sv = (unsigned)src[e];
    csr_src[p] = (sv < NN) ? (int)sv : 0;
  }
}

// ---------------- weight prep (fused): k_prep (blocks 0..1023) + k_prep_ub (1024..2047)
__global__ void k_prep(const void* __restrict__ w_src, const void* __restrict__ w_dst,
                       const void* __restrict__ w_hh, const void* __restrict__ wih,
                       const void* __restrict__ mlp_w, const void* __restrict__ mlp_b,
                       const void* __restrict__ b_ih, const void* __restrict__ b_hh,
                       const void* __restrict__ att, const void* __restrict__ gbias,
                       const void* __restrict__ init_w, const void* __restrict__ init_b,
                       const void* __restrict__ out_w, const void* __restrict__ out_b,
                       const int* __restrict__ flag,
                       __hip_bfloat16* __restrict__ wsrcT, __hip_bfloat16* __restrict__ wdstT,
                       __hip_bfloat16* __restrict__ whhp, __hip_bfloat16* __restrict__ wihb,
                       __hip_bfloat16* __restrict__ mlpT,
                       float* __restrict__ u, float* __restrict__ bc,
                       float* __restrict__ attf, float* __restrict__ gbiasf,
                       float* __restrict__ initwf, float* __restrict__ outwf,
                       float* __restrict__ sc){
  int f = *flag;
  if(blockIdx.x < 1024){
    int tid = blockIdx.x*256 + threadIdx.x;
    if(tid < 131072){
      int l = tid >> 16, r = tid & 65535, o = r >> 8, i = r & 255;
      wsrcT[tid] = f2bf(rdf(w_src, l*65536 + i*256 + o, f));
      wdstT[tid] = f2bf(rdf(w_dst, l*65536 + i*256 + o, f));
    }
    if(tid < 262144){
      whhp[tid] = f2bf(rdf(w_hh, tid, f));
      wihb[tid] = f2bf(rdf(wih, tid, f));
    }
    if(tid < 65536){
      int k = tid >> 8, j = tid & 255;
      mlpT[tid] = f2bf(rdf(mlp_w, j*257 + 1 + k, f));
    }
  }else{
    __shared__ float su[256], sb[256];
    int g = blockIdx.x - 1024, j = threadIdx.x;
    float w = rdf(wih, g*256 + j, f);
    su[j] = w * rdf(mlp_w, j*257, f);
    sb[j] = w * rdf(mlp_b, j, f);
    if(g < 2){
      int i = g*256 + j;
      attf[i] = rdf(att, i, f);
      gbiasf[i] = rdf(gbias, i, f);
    }
    if(g == 0){
      initwf[j] = rdf(init_w, j, f);
      outwf[j]  = rdf(out_w, j, f);
      if(j == 0){ sc[0] = rdf(init_b, 0, f); sc[1] = rdf(out_b, 0, f); }
    }
    __syncthreads();
    for(int s=128; s>0; s>>=1){
      if(j < s){ su[j] += su[j+s]; sb[j] += sb[j+s]; }
      __syncthreads();
    }
    if(j == 0){ u[g] = su[0]; bc[g] = sb[0] + rdf(b_ih, g, f) + rdf(b_hh, g, f); }
  }
}

// ---------------- combined packs: pack3 (blocks 0..127) + pack2 (blocks 128..255) ----
// pack3: gate-interleaved column halves + INLINE rank-1 fold (Whh2 = Whh + u(x)out_w).
// pack2: 4 projection matrices into dual-gemm fragment order.
__global__ void k_packs(const __hip_bfloat16* __restrict__ Wpl,
                        const __hip_bfloat16* __restrict__ Wcpl,
                        const float* __restrict__ u_vec, const float* __restrict__ outwf,
                        const __hip_bfloat16* __restrict__ wsrcT,
                        const __hip_bfloat16* __restrict__ wdstT,
                        __hip_bfloat16* __restrict__ WhhP, __hip_bfloat16* __restrict__ Whh2P,
                        __hip_bfloat16* __restrict__ WcP,
                        __hip_bfloat16* __restrict__ wprojP){
  if(blockIdx.x < 128){
    int idx = blockIdx.x*256 + threadIdx.x;   // 0..32767
    int P    = idx >> 14;
    int cs   = (idx >> 11) & 7;
    int kidx = (idx >> 8) & 7;
    int ntl  = (idx >> 6) & 3;
    int lane = idx & 63;
    int l16 = lane & 15, quad = lane >> 4;
    int brow = ntl*256 + P*128 + cs*16 + l16;
    int col0 = kidx*32 + quad*8;
    int srcofs = brow*256 + col0;
    int dst = idx*8;
    bf16x8 wv = LD8(Wpl + srcofs);
    *(bf16x8*)(WhhP + dst) = wv;
    float uu = u_vec[brow];
    bf16x8 w2;
    #pragma unroll
    for(int jj=0;jj<8;jj++)
      w2[jj] = (__bf16)f2bf(bf2f((__hip_bfloat16)wv[jj]) + uu*outwf[col0 + jj]);
    *(bf16x8*)(Whh2P + dst) = w2;
    *(bf16x8*)(WcP + dst)   = LD8(Wcpl + srcofs);
  }else{
    int idx = (blockIdx.x - 128)*256 + threadIdx.x;   // 0..32767
    int m = idx >> 13;
    int fi = idx & 8191;
    int l = m >> 1, role = m & 1;
    int kidx = fi >> 10;
    int nt = (fi >> 6) & 15;
    int lane = fi & 63;
    int l16 = lane & 15, quad = lane >> 4;
    const __hip_bfloat16* src = (role ? wdstT : wsrcT) + l*65536;
    int srcofs = (nt*16 + l16)*256 + kidx*32 + quad*8;
    *(bf16x8*)(wprojP + (size_t)m*65536 + fi*8) = LD8(src + srcofs);
  }
}

// ---------------- NT GEMM: Cb[m,n] = sum_k A[m,k]*B[n,k], M parametrized --------------
__global__ __launch_bounds__(256) void k_gemm_nt_bf(const __hip_bfloat16* __restrict__ A,
                                                    const __hip_bfloat16* __restrict__ B,
                                                    __hip_bfloat16* __restrict__ Cb, int M){
  int wave = threadIdx.x >> 6;
  int lane = threadIdx.x & 63;
  int l16 = lane & 15, quad = lane >> 4, quad8 = quad*8;
  int mBase = blockIdx.x*64 + wave*16;
  int nBase = blockIdx.y*64;
  int arow = mBase + l16; if(arow >= M) arow = M-1;
  const __hip_bfloat16* aptr = A + (size_t)arow*256 + quad8;
  float4v acc[4];
  #pragma unroll
  for(int nt=0;nt<4;nt++){ acc[nt][0]=0.f; acc[nt][1]=0.f; acc[nt][2]=0.f; acc[nt][3]=0.f; }
  for(int k0=0;k0<256;k0+=32){
    bf16x8 a = LD8(aptr + k0);
    #pragma unroll
    for(int nt=0;nt<4;nt++){
      const __hip_bfloat16* bptr = B + (size_t)(nBase + nt*16 + l16)*256 + k0 + quad8;
      acc[nt] = MFMA16(a, LD8(bptr), acc[nt]);
    }
  }
  #pragma unroll
  for(int nt=0;nt<4;nt++){
    int col = nBase + nt*16 + l16;
    #pragma unroll
    for(int r=0;r<4;r++){
      int row = mBase + quad*4 + r;
      if(row < M) Cb[(size_t)row*256 + col] = f2bf(acc[nt][r]);
    }
  }
}

// ---------------- dual projection GEMM: Q = A@Bsrc^T, P = A@Bdst^T (in-place) --------
__global__ __launch_bounds__(512, 2) void k_gemm_dual(__hip_bfloat16* __restrict__ P,
                                                      const void* __restrict__ xraw,
                                                      const int* __restrict__ flag,
                                                      int layer0,
                                                      const __hip_bfloat16* __restrict__ BsrcP,
                                                      const __hip_bfloat16* __restrict__ BdstP,
                                                      __hip_bfloat16* __restrict__ Q){
  __shared__ __hip_bfloat16 sA[64*264];
  int tid = threadIdx.x;
  int mBase = blockIdx.x*64;
  {
    int r = tid >> 3;
    int c0 = (tid & 7)*32;
    int grow = mBase + r; if(grow >= NN) grow = NN-1;
    if(layer0){
      int f = *flag;
      #pragma unroll
      for(int j=0;j<32;j++) sA[r*264 + c0 + j] = f2bf(rdf(xraw, grow*256 + c0 + j, f));
    }else{
      const __hip_bfloat16* srcp = P + (size_t)grow*256 + c0;
      #pragma unroll
      for(int j=0;j<4;j++) *(bf16x8*)(&sA[r*264 + c0 + j*8]) = LD8(srcp + j*8);
    }
  }
  __syncthreads();
  int w8 = tid >> 6;
  int w = w8 & 3;
  int role = w8 >> 2;
  int lane = tid&63, l16 = lane&15, quad = lane>>4, quad8 = quad*8;
  const __hip_bfloat16* B = role ? BdstP : BsrcP;
  __hip_bfloat16* C = role ? P : Q;
  const __hip_bfloat16* arow = &sA[(w*16 + l16)*264 + quad8];
  float4v acc[16];
  #pragma unroll
  for(int nt=0;nt<16;nt++){ acc[nt][0]=0.f; acc[nt][1]=0.f; acc[nt][2]=0.f; acc[nt][3]=0.f; }
  for(int kidx=0;kidx<8;kidx++){
    bf16x8 a = *(const bf16x8*)(arow + kidx*32);
    const __hip_bfloat16* bbase = B + (kidx<<13) + (lane<<3);
    #pragma unroll
    for(int nt=0;nt<16;nt++)
      acc[nt] = MFMA16(a, LD8(bbase + (nt<<9)), acc[nt]);
  }
  #pragma unroll
  for(int nt=0;nt<16;nt++){
    int col = nt*16 + l16;
    #pragma unroll
    for(int r=0;r<4;r++){
      int row = mBase + w*16 + quad*4 + r;
      if(row < NN) C[(size_t)row*256 + col] = f2bf(acc[nt][r]);
    }
  }
}

// ---------------- GAT edge phase: two-pass, 10 nodes per block ----------------------
// r13: NPB 4->10 (grid 2000, ~8 blocks/CU) to amortize per-block fixed costs further
// (r12 proved the mechanism: +NPB=4 saved ~35us over two layers). Phase structure and
// logits form unchanged from r12 (correctness-proven).
__global__ __launch_bounds__(256) void k_node_fused(const __hip_bfloat16* __restrict__ Q,
                                                    __hip_bfloat16* __restrict__ P,
                                                    const int* __restrict__ offp,
                                                    const int* __restrict__ csr_src,
                                                    const float* __restrict__ attf,
                                                    const float* __restrict__ gbiasf){
  __shared__ float slog[DEGMAX*4];
  __shared__ int ssrc[DEGMAX];
  int tid = threadIdx.x;
  int w = tid>>6, lane = tid&63;
  int eSlot = lane>>4, li = lane&15;   // 16-lane group per edge; lane owns d=li*16..+15
  float attl[16];
  #pragma unroll
  for(int j=0;j<16;j++) attl[j] = attf[li*16 + j];
  float gb = gbiasf[tid];
  int hd = tid>>6;
  #pragma unroll 1
  for(int nn=0; nn<NPB; nn++){
    int node = blockIdx.x*NPB + nn;
    int s0 = offp[node], s1 = offp[node+1];
    if(s0 < 0) s0 = 0; if(s0 > NE) s0 = NE;
    if(s1 < s0) s1 = s0; if(s1 > NE) s1 = NE;
    int deg = s1 - s0; if(deg > DEGMAX) deg = DEGMAX;
    if(tid < deg){
      unsigned sv = (unsigned)csr_src[s0 + tid];
      ssrc[tid] = (sv < NN) ? (int)sv : 0;
    }
    __syncthreads();
    float prl[16];
    {
      const __hip_bfloat16* prow = P + (size_t)node*256 + li*16;
      bf16x8 p0 = LD8(prow), p1 = LD8(prow + 8);
      #pragma unroll
      for(int j=0;j<8;j++){ prl[j] = bf2f((__hip_bfloat16)p0[j]); prl[8+j] = bf2f((__hip_bfloat16)p1[j]); }
    }
    for(int base=0; base<deg; base+=16){
      int e = base + w*4 + eSlot;
      bool valid = (e < deg);
      const __hip_bfloat16* qrow = Q + (size_t)ssrc[valid ? e : 0]*256 + li*16;
      bf16x8 q0 = LD8(qrow), q1 = LD8(qrow + 8);
      float part = 0.f;
      #pragma unroll
      for(int j=0;j<16;j++){
        float v = bf2f((__hip_bfloat16)(j<8 ? q0[j] : q1[j-8])) + prl[j];
        v = (v > 0.f) ? v : 0.2f*v;
        part += v * attl[j];
      }
      part += __shfl_xor(part, 1, 64);
      part += __shfl_xor(part, 2, 64);
      if((li & 3) == 0 && valid) slog[e*4 + (li>>2)] = part;
    }
    __syncthreads();
    {
      int hh = tid >> 6;          // one wave per head
      int li64 = tid & 63;
      float m = -1e30f;
      for(int i=li64; i<deg; i+=64) m = fmaxf(m, slog[i*4+hh]);
      #pragma unroll
      for(int s=1; s<64; s<<=1) m = fmaxf(m, __shfl_xor(m, s, 64));
      float den = 0.f;
      for(int i=li64; i<deg; i+=64) den += __expf(slog[i*4+hh] - m);
      #pragma unroll
      for(int s=1; s<64; s<<=1) den += __shfl_xor(den, s, 64);
      float inv = (den > 0.f) ? 1.f/den : 0.f;
      for(int i=li64; i<deg; i+=64) slog[i*4+hh] = __expf(slog[i*4+hh] - m)*inv;
    }
    __syncthreads();
    float acc = 0.f;
    for(int i=0;i<deg;i++) acc += slog[i*4+hd] * bf2f(Q[(size_t)ssrc[i]*256 + tid]);
    acc += gb;
    acc = (acc > 0.f) ? acc : (__expf(acc) - 1.f);   // ELU
    P[(size_t)node*256 + tid] = f2bf(acc);
    __syncthreads();   // protect ssrc/slog reuse by next node
  }
}

// ---------------- persistent LSTM v6b (r8, PROVEN ~272us): hidden-half split ---------
// 2 waves/SIMD 256-reg regime is the only spill-clean one (r9 MR32 + r10 16-wave both
// spilled at the 128-reg cap). gateB chunk map: cpa EVEN {10,12,14,16,18} ->
// sgx/gg1/gg3/gg5; cpb_ ODD {11,13,15,17,19} -> sgx/gg0/gg2/gg4/gg6.
__global__ __launch_bounds__(512, 1) void k_lstm80(const __hip_bfloat16* __restrict__ ctx,
                                                   const __hip_bfloat16* __restrict__ WcP,
                                                   const __hip_bfloat16* __restrict__ WhhP,
                                                   const __hip_bfloat16* __restrict__ Whh2P,
                                                   const float* __restrict__ u_vec,
                                                   const float* __restrict__ bc_vec,
                                                   const float* __restrict__ initwf,
                                                   const float* __restrict__ outwf,
                                                   const float* __restrict__ sc,
                                                   float* __restrict__ out){
  __shared__ __hip_bfloat16 sgx[NCPL*4096]; // 106,496B GX chunks [cp][thread][8]
  __shared__ __hip_bfloat16 sh[MR*264];     // 42,240B h tile (bank-padded)
  __shared__ float spartw[2][MR*16];        // 10,240B out-proj partials (step-parity dbuf)
  __shared__ float sprev0[MR];              // 320B step-0 prev
  float* spart = (float*)sgx;               // prologue-only overlay (2KB of sgx)
  int tid = threadIdx.x;
  int mBase = blockIdx.x*MR;
  int cs = tid>>6, lane = tid&63, l16 = lane&15, quad = lane>>4, quad8 = quad*8;
  int phase = (blockIdx.x >> 3) & 7;
  int j0 = cs*16 + l16;          // phase-A hidden dim
  int j1 = 128 + j0;             // phase-B hidden dim
  // load h0 = ctx tile
  #pragma unroll
  for(int p=0;p<3;p++){
    int r = p*32 + (tid >> 4);
    if(r < MR){
      int c0 = (tid & 15)*16;
      const __hip_bfloat16* srcp = ctx + (size_t)(mBase + r)*256 + c0;
      *(bf16x8*)(&sh[r*264 + c0])     = LD8(srcp);
      *(bf16x8*)(&sh[r*264 + c0 + 8]) = LD8(srcp + 8);
    }
  }
  __syncthreads();
  // prev0 = ctx @ init_w + init_b   (spart overlays sgx; reads done before GX writes)
  #pragma unroll
  for(int p=0;p<3;p++){
    int r = p*32 + (tid >> 4);
    int c0 = (tid & 15)*16;
    float part = 0.f;
    if(r < MR){
      #pragma unroll
      for(int j=0;j<16;j++) part += bf2f(sh[r*264 + c0 + j]) * initwf[c0 + j];
    }
    spart[tid] = part;
    __syncthreads();
    if(tid < 32 && p*32 + tid < MR){
      float s = 0.f;
      #pragma unroll
      for(int j=0;j<16;j++) s += spart[tid*16 + j];
      sprev0[p*32 + tid] = s + sc[0];
    }
    __syncthreads();
  }
  float ow0 = outwf[j0], ow1 = outwf[j1];
  float outb = sc[1];
  // GX phase: GX' = ctx@Wc^T + bc + u*out_b, fragment layout = step layout.
  // cp = P*10 + rt*2 + half; cp 0..12 -> LDS, 13..19 -> gg0..gg6
  bf16x8 gg0, gg1, gg2, gg3, gg4, gg5, gg6;
  {
    float bcl[8];   // [P*4+g]
    #pragma unroll
    for(int g=0;g<4;g++){
      bcl[g]   = bc_vec[g*256 + j0] + u_vec[g*256 + j0]*outb;
      bcl[4+g] = bc_vec[g*256 + j1] + u_vec[g*256 + j1]*outb;
    }
    #pragma unroll
    for(int P2=0;P2<2;P2++){
      float4v acc[20];
      #pragma unroll
      for(int nt=0;nt<20;nt++){ acc[nt][0]=0.f; acc[nt][1]=0.f; acc[nt][2]=0.f; acc[nt][3]=0.f; }
      #pragma unroll 2
      for(int ki=0;ki<8;ki++){
        int kidx = (ki + phase) & 7;
        int k0 = kidx*32;
        bf16x8 a0 = *(const bf16x8*)(&sh[l16*264 + k0 + quad8]);
        bf16x8 a1 = *(const bf16x8*)(&sh[(16 + l16)*264 + k0 + quad8]);
        bf16x8 a2 = *(const bf16x8*)(&sh[(32 + l16)*264 + k0 + quad8]);
        bf16x8 a3 = *(const bf16x8*)(&sh[(48 + l16)*264 + k0 + quad8]);
        bf16x8 a4 = *(const bf16x8*)(&sh[(64 + l16)*264 + k0 + quad8]);
        const __hip_bfloat16* bbase = WcP + P2*131072 + (((cs<<3) + kidx)<<11) + (lane<<3);
        #pragma unroll
        for(int ntl=0;ntl<4;ntl++){
          bf16x8 b = LD8(bbase + (ntl<<9));
          acc[ntl]     = MFMA16(a0, b, acc[ntl]);
          acc[4+ntl]   = MFMA16(a1, b, acc[4+ntl]);
          acc[8+ntl]   = MFMA16(a2, b, acc[8+ntl]);
          acc[12+ntl]  = MFMA16(a3, b, acc[12+ntl]);
          acc[16+ntl]  = MFMA16(a4, b, acc[16+ntl]);
        }
      }
      #pragma unroll
      for(int rt=0;rt<5;rt++)
        #pragma unroll
        for(int half=0;half<2;half++){
          bf16x8 v;
          #pragma unroll
          for(int rr=0;rr<2;rr++)
            #pragma unroll
            for(int g=0;g<4;g++){
              int r = half*2 + rr;
              v[rr*4+g] = (__bf16)f2bf(acc[rt*4 + g][r] + bcl[P2*4+g]);
            }
          const int cp = P2*10 + rt*2 + half;   // compile-time
          if(cp < NCPL) *(bf16x8*)(&sgx[cp*4096 + tid*8]) = v;
          else if(cp == 13) gg0 = v;
          else if(cp == 14) gg1 = v;
          else if(cp == 15) gg2 = v;
          else if(cp == 16) gg3 = v;
          else if(cp == 17) gg4 = v;
          else if(cp == 18) gg5 = v;
          else              gg6 = v;
        }
    }
  }
  // no barrier: sgx slots are own-thread; sh unmodified until step-0 gateB (after S1)
  float creg[40];   // [P*20 + rt*4 + r]
  #pragma unroll
  for(int i=0;i<40;i++) creg[i] = 0.f;
  #pragma unroll 1
  for(int step=0; step<TOUT; step++){
    const __hip_bfloat16* W = (step == 0) ? WhhP : Whh2P;
    int sb = step & 1;
    float4v acc[20];
    // ---- MFMA-A: hidden half 0 (W cols 0..511 repacked) ----
    #pragma unroll
    for(int nt=0;nt<20;nt++){ acc[nt][0]=0.f; acc[nt][1]=0.f; acc[nt][2]=0.f; acc[nt][3]=0.f; }
    #pragma unroll 2
    for(int ki=0;ki<8;ki++){
      int kidx = (ki + phase) & 7;
      int k0 = kidx*32;
      bf16x8 a0 = *(const bf16x8*)(&sh[l16*264 + k0 + quad8]);
      bf16x8 a1 = *(const bf16x8*)(&sh[(16 + l16)*264 + k0 + quad8]);
      bf16x8 a2 = *(const bf16x8*)(&sh[(32 + l16)*264 + k0 + quad8]);
      bf16x8 a3 = *(const bf16x8*)(&sh[(48 + l16)*264 + k0 + quad8]);
      bf16x8 a4 = *(const bf16x8*)(&sh[(64 + l16)*264 + k0 + quad8]);
      const __hip_bfloat16* bbase = W + (((cs<<3) + kidx)<<11) + (lane<<3);
      #pragma unroll
      for(int ntl=0;ntl<4;ntl++){
        bf16x8 b = LD8(bbase + (ntl<<9));
        acc[ntl]     = MFMA16(a0, b, acc[ntl]);
        acc[4+ntl]   = MFMA16(a1, b, acc[4+ntl]);
        acc[8+ntl]   = MFMA16(a2, b, acc[8+ntl]);
        acc[12+ntl]  = MFMA16(a3, b, acc[12+ntl]);
        acc[16+ntl]  = MFMA16(a4, b, acc[16+ntl]);
      }
    }
    // ---- gateA: finish hidden half 0; h held in regs (sh still readable by B) ----
    float hA[20];
    #pragma unroll
    for(int rt=0; rt<5; rt++){
      bf16x8 ga = *(const bf16x8*)(&sgx[(rt*2)*4096 + tid*8]);
      bf16x8 gb = *(const bf16x8*)(&sgx[(rt*2+1)*4096 + tid*8]);
      float hsum[4];
      #pragma unroll
      for(int r=0;r<4;r++){
        int row = rt*16 + quad*4 + r;
        int jb = (r&1)*4;
        float gx0, gx1, gx2, gx3;
        if(r < 2){
          gx0 = bf2f((__hip_bfloat16)ga[jb]);   gx1 = bf2f((__hip_bfloat16)ga[jb+1]);
          gx2 = bf2f((__hip_bfloat16)ga[jb+2]); gx3 = bf2f((__hip_bfloat16)ga[jb+3]);
        }else{
          gx0 = bf2f((__hip_bfloat16)gb[jb]);   gx1 = bf2f((__hip_bfloat16)gb[jb+1]);
          gx2 = bf2f((__hip_bfloat16)gb[jb+2]); gx3 = bf2f((__hip_bfloat16)gb[jb+3]);
        }
        float g0 = acc[rt*4 + 0][r] + gx0;
        float g1 = acc[rt*4 + 1][r] + gx1;
        float g2 = acc[rt*4 + 2][r] + gx2;
        float g3 = acc[rt*4 + 3][r] + gx3;
        if(step == 0){
          float pd = sprev0[row] - outb;   // stored GX includes +u*out_b
          g0 += pd*u_vec[j0];
          g1 += pd*u_vec[256 + j0];
          g2 += pd*u_vec[512 + j0];
          g3 += pd*u_vec[768 + j0];
        }
        float iv = sigmoidr_(g0), fv = sigmoidr_(g1);
        float gv = tanhr_(g2),    ov = sigmoidr_(g3);
        float cn = fv*creg[rt*4 + r] + iv*gv;
        creg[rt*4 + r] = cn;
        float hn = ov * tanhr_(cn);
        hA[rt*4 + r] = hn;
        hsum[r] = hn * ow0;
      }
      #pragma unroll
      for(int r=0;r<4;r++){
        hsum[r] += __shfl_xor(hsum[r], 1, 64);
        hsum[r] += __shfl_xor(hsum[r], 2, 64);
        hsum[r] += __shfl_xor(hsum[r], 4, 64);
        hsum[r] += __shfl_xor(hsum[r], 8, 64);
      }
      if(l16 == 0){
        #pragma unroll
        for(int r=0;r<4;r++)
          spartw[sb][(rt*16 + quad*4 + r)*16 + cs*2] = hsum[r];
      }
    }
    // ---- MFMA-B: hidden half 1 (W cols 512..1023 repacked), acc regs reused ----
    #pragma unroll
    for(int nt=0;nt<20;nt++){ acc[nt][0]=0.f; acc[nt][1]=0.f; acc[nt][2]=0.f; acc[nt][3]=0.f; }
    #pragma unroll 2
    for(int ki=0;ki<8;ki++){
      int kidx = (ki + phase) & 7;
      int k0 = kidx*32;
      bf16x8 a0 = *(const bf16x8*)(&sh[l16*264 + k0 + quad8]);
      bf16x8 a1 = *(const bf16x8*)(&sh[(16 + l16)*264 + k0 + quad8]);
      bf16x8 a2 = *(const bf16x8*)(&sh[(32 + l16)*264 + k0 + quad8]);
      bf16x8 a3 = *(const bf16x8*)(&sh[(48 + l16)*264 + k0 + quad8]);
      bf16x8 a4 = *(const bf16x8*)(&sh[(64 + l16)*264 + k0 + quad8]);
      const __hip_bfloat16* bbase = W + 131072 + (((cs<<3) + kidx)<<11) + (lane<<3);
      #pragma unroll
      for(int ntl=0;ntl<4;ntl++){
        bf16x8 b = LD8(bbase + (ntl<<9));
        acc[ntl]     = MFMA16(a0, b, acc[ntl]);
        acc[4+ntl]   = MFMA16(a1, b, acc[4+ntl]);
        acc[8+ntl]   = MFMA16(a2, b, acc[8+ntl]);
        acc[12+ntl]  = MFMA16(a3, b, acc[12+ntl]);
        acc[16+ntl]  = MFMA16(a4, b, acc[16+ntl]);
      }
    }
    __syncthreads();   // S1: all sh reads of this step done (A and B phases)
    // ---- gateB: finish hidden half 1; write BOTH h halves into sh ----
    #pragma unroll
    for(int rt=0; rt<5; rt++){
      const int cpa = 10 + rt*2, cpb_ = 11 + rt*2;
      // cpa is EVEN: {10,12,14,16,18}; cpb_ is ODD: {11,13,15,17,19}
      bf16x8 ga, gb;
      if(cpa < NCPL)      ga = *(const bf16x8*)(&sgx[cpa*4096 + tid*8]);   // 10,12
      else if(cpa == 14)  ga = gg1;
      else if(cpa == 16)  ga = gg3;
      else                ga = gg5;    // cpa == 18
      if(cpb_ < NCPL)     gb = *(const bf16x8*)(&sgx[cpb_*4096 + tid*8]);  // 11
      else if(cpb_ == 13) gb = gg0;
      else if(cpb_ == 15) gb = gg2;
      else if(cpb_ == 17) gb = gg4;
      else                gb = gg6;    // cpb_ == 19
      float hsum[4];
      #pragma unroll
      for(int r=0;r<4;r++){
        int row = rt*16 + quad*4 + r;
        int jb = (r&1)*4;
        float gx0, gx1, gx2, gx3;
        if(r < 2){
          gx0 = bf2f((__hip_bfloat16)ga[jb]);   gx1 = bf2f((__hip_bfloat16)ga[jb+1]);
          gx2 = bf2f((__hip_bfloat16)ga[jb+2]); gx3 = bf2f((__hip_bfloat16)ga[jb+3]);
        }else{
          gx0 = bf2f((__hip_bfloat16)gb[jb]);   gx1 = bf2f((__hip_bfloat16)gb[jb+1]);
          gx2 = bf2f((__hip_bfloat16)gb[jb+2]); gx3 = bf2f((__hip_bfloat16)gb[jb+3]);
        }
        float g0 = acc[rt*4 + 0][r] + gx0;
        float g1 = acc[rt*4 + 1][r] + gx1;
        float g2 = acc[rt*4 + 2][r] + gx2;
        float g3 = acc[rt*4 + 3][r] + gx3;
        if(step == 0){
          float pd = sprev0[row] - outb;
          g0 += pd*u_vec[j1];
          g1 += pd*u_vec[256 + j1];
          g2 += pd*u_vec[512 + j1];
          g3 += pd*u_vec[768 + j1];
        }
        float iv = sigmoidr_(g0), fv = sigmoidr_(g1);
        float gv = tanhr_(g2),    ov = sigmoidr_(g3);
        float cn = fv*creg[20 + rt*4 + r] + iv*gv;
        creg[20 + rt*4 + r] = cn;
        float hn = ov * tanhr_(cn);
        sh[row*264 + j0] = f2bf(hA[rt*4 + r]);
        sh[row*264 + j1] = f2bf(hn);
        hsum[r] = hn * ow1;
      }
      #pragma unroll
      for(int r=0;r<4;r++){
        hsum[r] += __shfl_xor(hsum[r], 1, 64);
        hsum[r] += __shfl_xor(hsum[r], 2, 64);
        hsum[r] += __shfl_xor(hsum[r], 4, 64);
        hsum[r] += __shfl_xor(hsum[r], 8, 64);
      }
      if(l16 == 0){
        #pragma unroll
        for(int r=0;r<4;r++)
          spartw[sb][(rt*16 + quad*4 + r)*16 + cs*2 + 1] = hsum[r];
      }
    }
    __syncthreads();   // S2: sh + spartw writes visible
    if(tid < MR){
      float s = outb;
      #pragma unroll
      for(int c=0;c<16;c++) s += spartw[sb][tid*16 + c];
      out[(size_t)(mBase + tid)*TOUT + step] = s;
    }
    // next step's gateA writes spartw[sb^1] -> no hazard with this reduce
  }
}

// ---------------- launch ----------------
extern "C" void kernel_launch(void* const* d_in, const int* in_sizes, int n_in,
                              void* d_out, int out_size, void* d_ws, size_t ws_size,
                              hipStream_t stream){
  const void* x      = d_in[0];
  const int*  ei     = (const int*)d_in[1];
  const void* w_src  = d_in[2];
  const void* w_dst  = d_in[3];
  const void* att    = d_in[4];
  const void* gbias  = d_in[5];
  const void* mlp_w  = d_in[6];
  const void* mlp_b  = d_in[7];
  const void* w_ih   = d_in[8];
  const void* w_hh   = d_in[9];
  const void* b_ih   = d_in[10];
  const void* b_hh   = d_in[11];
  const void* init_w = d_in[12];
  const void* init_b = d_in[13];
  const void* out_w  = d_in[14];
  const void* out_b  = d_in[15];
  float* out = (float*)d_out;
  const int* srcp = ei;
  const int* dstp = ei + NE;
  (void)in_sizes; (void)n_in;

  char* ws = (char*)d_ws;
  size_t off = 0;
  auto alloc = [&](size_t bytes)->void*{
    void* p = ws + off;
    off += (bytes + 255) & ~(size_t)255;
    return p;
  };
  __hip_bfloat16* P = (__hip_bfloat16*)alloc((size_t)NN*256*2);
  __hip_bfloat16* Q = (__hip_bfloat16*)alloc((size_t)NN*256*2);
  int* deg      = (int*)alloc((size_t)NN*4);
  int* offp     = (int*)alloc((size_t)(NN+1)*4);
  int* cursor   = (int*)alloc((size_t)NN*4);
  int* csr_src  = (int*)alloc((size_t)NE*4);
  __hip_bfloat16* wsrcT   = (__hip_bfloat16*)alloc((size_t)131072*2);
  __hip_bfloat16* wdstT   = (__hip_bfloat16*)alloc((size_t)131072*2);
  __hip_bfloat16* wprojP  = (__hip_bfloat16*)alloc((size_t)4*65536*2);
  __hip_bfloat16* whh_pl  = (__hip_bfloat16*)alloc((size_t)262144*2);
  __hip_bfloat16* Wc_pl   = (__hip_bfloat16*)alloc((size_t)262144*2);
  __hip_bfloat16* WhhP    = (__hip_bfloat16*)alloc((size_t)262144*2);
  __hip_bfloat16* Whh2P   = (__hip_bfloat16*)alloc((size_t)262144*2);
  __hip_bfloat16* WcP     = (__hip_bfloat16*)alloc((size_t)262144*2);
  __hip_bfloat16* wihb    = (__hip_bfloat16*)alloc((size_t)262144*2);
  __hip_bfloat16* mlpT    = (__hip_bfloat16*)alloc((size_t)65536*2);
  float* u_vec  = (float*)alloc(1024*4);
  float* bc_vec = (float*)alloc(1024*4);
  float* attf   = (float*)alloc(512*4);
  float* gbiasf = (float*)alloc(512*4);
  float* initwf = (float*)alloc(256*4);
  float* outwf  = (float*)alloc(256*4);
  float* sc     = (float*)alloc(2*4);
  int*   flag   = (int*)alloc(4);
  // total ~28 MB

  if(off > ws_size){
    k_fail<<<(out_size + 255)/256, 256, 0, stream>>>(out, out_size);
    return;
  }

  // dtype detect + CSR + prep
  k_detect<<<1, 256, 0, stream>>>(x, flag);
  hipMemsetAsync(deg, 0, (size_t)NN*4, stream);
  hipMemsetAsync(csr_src, 0xFF, (size_t)NE*4, stream);
  k_count<<<NE/256, 256, 0, stream>>>(dstp, deg);
  k_scan<<<1, 256, 0, stream>>>(deg, offp, cursor);
  k_fill<<<NE/256, 256, 0, stream>>>(srcp, dstp, cursor, csr_src);
  k_prep<<<2048, 256, 0, stream>>>(w_src, w_dst, w_hh, w_ih, mlp_w, mlp_b,
                                   b_ih, b_hh, att, gbias, init_w, init_b,
                                   out_w, out_b, flag,
                                   wsrcT, wdstT, whh_pl, wihb, mlpT,
                                   u_vec, bc_vec, attf, gbiasf, initwf, outwf, sc);
  {
    dim3 gwc(16, 4);
    k_gemm_nt_bf<<<gwc, 256, 0, stream>>>(wihb, mlpT, Wc_pl, 1024);   // Wc = Wih @ mlpT^T
  }
  k_packs<<<256, 256, 0, stream>>>(whh_pl, Wc_pl, u_vec, outwf, wsrcT, wdstT,
                                   WhhP, Whh2P, WcP, wprojP);

  // GAT layers: dual projection (layer0 reads raw x), then two-pass edge phase
  for(int l=0;l<2;l++){
    k_gemm_dual<<<313, 512, 0, stream>>>(P, x, flag, (l == 0) ? 1 : 0,
                                         wprojP + (size_t)(l*2)*65536,
                                         wprojP + (size_t)(l*2+1)*65536, Q);
    k_node_fused<<<NN/NPB, 256, 0, stream>>>(Q, P, offp, csr_src, attf + l*256, gbiasf + l*256);
  }

  // persistent LSTM decoder: hidden-half split, disjoint streams, single round (r8)
  k_lstm80<<<NBLK, 512, 0, stream>>>(P, WcP, WhhP, Whh2P, u_vec, bc_vec,
                                     initwf, outwf, sc, out);
}